// Round 1
// baseline (12483.974 us; speedup 1.0000x reference)
//
#include <hip/hip_runtime.h>
#include <math.h>

#define N_NODES 100000
#define N_EDGES 1600000
#define H 128
#define F 64

// ---------------------------------------------------------------- init h ----
// h[i][0:64] = features[i], h[i][64:128] = 0   (one float4 per thread)
__global__ __launch_bounds__(256) void init_h_kernel(const float* __restrict__ f,
                                                     float* __restrict__ h) {
    int idx = blockIdx.x * 256 + threadIdx.x;          // over N*32 float4
    if (idx >= N_NODES * 32) return;
    int r = idx >> 5, c4 = idx & 31;
    float4 v = make_float4(0.f, 0.f, 0.f, 0.f);
    if (c4 < 16) v = ((const float4*)f)[r * 16 + c4];
    ((float4*)h)[idx] = v;
}

__global__ __launch_bounds__(256) void zero_a_kernel(float* __restrict__ a) {
    int idx = blockIdx.x * 256 + threadIdx.x;
    if (idx < N_NODES * 32) ((float4*)a)[idx] = make_float4(0.f, 0.f, 0.f, 0.f);
}

// ---------------------------------------------------------------- hw GEMM ---
// hw = h @ W.T      [N,128] x [128,128]
// 64-row tile per block, 256 threads, each thread 4 rows x 8 cols.
// LDS strides padded (132 / 36) -> <=2-way bank conflicts (free).
__global__ __launch_bounds__(256, 2) void gemm_hw_kernel(const float* __restrict__ h,
                                                         const float* __restrict__ W,
                                                         float* __restrict__ hw) {
    __shared__ float As[64][132];
    __shared__ float Ws[128][36];
    const int tid = threadIdx.x;
    const int row0 = blockIdx.x * 64;
    const int cg = tid & 15, rg = tid >> 4;

#pragma unroll
    for (int i = 0; i < 8; ++i) {                       // stage A tile (64x128)
        int idx = tid + 256 * i;
        int r = idx >> 5, c4 = idx & 31;
        int gr = row0 + r; if (gr >= N_NODES) gr = N_NODES - 1;
        *(float4*)&As[r][c4 * 4] = ((const float4*)h)[gr * 32 + c4];
    }

    float acc[4][8] = {};
    for (int kc = 0; kc < 4; ++kc) {                    // K chunks of 32
        __syncthreads();
#pragma unroll
        for (int i = 0; i < 4; ++i) {                   // stage W chunk (128x32)
            int idx = tid + 256 * i;
            int c = idx >> 3, k4 = idx & 7;
            *(float4*)&Ws[c][k4 * 4] = ((const float4*)W)[c * 32 + kc * 8 + k4];
        }
        __syncthreads();
#pragma unroll
        for (int k = 0; k < 32; ++k) {
            float av[4], wv[8];
#pragma unroll
            for (int i = 0; i < 4; ++i) av[i] = As[rg + 16 * i][kc * 32 + k];
#pragma unroll
            for (int j = 0; j < 8; ++j) wv[j] = Ws[cg + 16 * j][k];
#pragma unroll
            for (int i = 0; i < 4; ++i)
#pragma unroll
                for (int j = 0; j < 8; ++j) acc[i][j] += av[i] * wv[j];
        }
    }
#pragma unroll
    for (int i = 0; i < 4; ++i) {
        int gr = row0 + rg + 16 * i;
        if (gr < N_NODES) {
#pragma unroll
            for (int j = 0; j < 8; ++j) hw[gr * 128 + cg + 16 * j] = acc[i][j];
        }
    }
}

// ---------------------------------------------------------------- scatter ---
// a[dst] += hw[src] + b     one (edge, 4-float-chunk) per thread.
__global__ __launch_bounds__(256) void scatter_kernel(const float* __restrict__ hw,
                                                      const float* __restrict__ b,
                                                      const int* __restrict__ src,
                                                      const int* __restrict__ dst,
                                                      float* __restrict__ a) {
    int idx = blockIdx.x * 256 + threadIdx.x;          // over E*32
    if (idx >= N_EDGES * 32) return;
    int e = idx >> 5, l = idx & 31;
    int s = src[e], d = dst[e];
    float4 v = ((const float4*)hw)[s * 32 + l];
    float4 bb = ((const float4*)b)[l];
    float* ap = a + (size_t)d * 128 + l * 4;
    atomicAdd(ap + 0, v.x + bb.x);
    atomicAdd(ap + 1, v.y + bb.y);
    atomicAdd(ap + 2, v.z + bb.z);
    atomicAdd(ap + 3, v.w + bb.w);
}

// ---------------------------------------------------------------- GRU -------
// gi = a @ W_ih.T ; gh = h @ W_hh.T ; gates ; h_new in-place.
__global__ __launch_bounds__(256, 2) void gru_kernel(const float* __restrict__ a,
                                                     const float* __restrict__ W_ih,
                                                     const float* __restrict__ W_hh,
                                                     const float* __restrict__ b_ih,
                                                     const float* __restrict__ b_hh,
                                                     float* __restrict__ h) {
    __shared__ float As[64][132];
    __shared__ float Ws[128][36];
    const int tid = threadIdx.x;
    const int row0 = blockIdx.x * 64;
    const int cg = tid & 15, rg = tid >> 4;

    // ---- stage a tile
#pragma unroll
    for (int i = 0; i < 8; ++i) {
        int idx = tid + 256 * i;
        int r = idx >> 5, c4 = idx & 31;
        int gr = row0 + r; if (gr >= N_NODES) gr = N_NODES - 1;
        *(float4*)&As[r][c4 * 4] = ((const float4*)a)[gr * 32 + c4];
    }

    float gi[3][4][8] = {};
    for (int g = 0; g < 3; ++g) {
        for (int kc = 0; kc < 4; ++kc) {
            __syncthreads();
#pragma unroll
            for (int i = 0; i < 4; ++i) {
                int idx = tid + 256 * i;
                int c = idx >> 3, k4 = idx & 7;
                *(float4*)&Ws[c][k4 * 4] =
                    ((const float4*)W_ih)[(g * 128 + c) * 32 + kc * 8 + k4];
            }
            __syncthreads();
#pragma unroll
            for (int k = 0; k < 32; ++k) {
                float av[4], wv[8];
#pragma unroll
                for (int i = 0; i < 4; ++i) av[i] = As[rg + 16 * i][kc * 32 + k];
#pragma unroll
                for (int j = 0; j < 8; ++j) wv[j] = Ws[cg + 16 * j][k];
#pragma unroll
                for (int i = 0; i < 4; ++i)
#pragma unroll
                    for (int j = 0; j < 8; ++j) gi[g][i][j] += av[i] * wv[j];
            }
        }
    }

    // ---- restage h tile (also serves as h_old for the final combine)
    __syncthreads();
#pragma unroll
    for (int i = 0; i < 8; ++i) {
        int idx = tid + 256 * i;
        int r = idx >> 5, c4 = idx & 31;
        int gr = row0 + r; if (gr >= N_NODES) gr = N_NODES - 1;
        *(float4*)&As[r][c4 * 4] = ((const float4*)h)[gr * 32 + c4];
    }

    for (int g = 0; g < 3; ++g) {
        float gh[4][8] = {};
        for (int kc = 0; kc < 4; ++kc) {
            __syncthreads();
#pragma unroll
            for (int i = 0; i < 4; ++i) {
                int idx = tid + 256 * i;
                int c = idx >> 3, k4 = idx & 7;
                *(float4*)&Ws[c][k4 * 4] =
                    ((const float4*)W_hh)[(g * 128 + c) * 32 + kc * 8 + k4];
            }
            __syncthreads();
#pragma unroll
            for (int k = 0; k < 32; ++k) {
                float av[4], wv[8];
#pragma unroll
                for (int i = 0; i < 4; ++i) av[i] = As[rg + 16 * i][kc * 32 + k];
#pragma unroll
                for (int j = 0; j < 8; ++j) wv[j] = Ws[cg + 16 * j][k];
#pragma unroll
                for (int i = 0; i < 4; ++i)
#pragma unroll
                    for (int j = 0; j < 8; ++j) gh[i][j] += av[i] * wv[j];
            }
        }
        // ---- fold this gate into gi storage
        float bih[8], bhh[8];
#pragma unroll
        for (int j = 0; j < 8; ++j) {
            bih[j] = b_ih[g * 128 + cg + 16 * j];
            bhh[j] = b_hh[g * 128 + cg + 16 * j];
        }
        if (g == 0 || g == 1) {        // r / z gates: sigmoid(gi + gh + biases)
#pragma unroll
            for (int i = 0; i < 4; ++i)
#pragma unroll
                for (int j = 0; j < 8; ++j) {
                    float x = gi[g][i][j] + bih[j] + gh[i][j] + bhh[j];
                    gi[g][i][j] = 1.f / (1.f + __expf(-x));
                }
        } else {                       // n gate + final combine + write
#pragma unroll
            for (int i = 0; i < 4; ++i) {
                int gr = row0 + rg + 16 * i;
                if (gr >= N_NODES) continue;
#pragma unroll
                for (int j = 0; j < 8; ++j) {
                    float r_ = gi[0][i][j];
                    float z_ = gi[1][i][j];
                    float n_ = tanhf(gi[2][i][j] + bih[j] + r_ * (gh[i][j] + bhh[j]));
                    float hold = As[rg + 16 * i][cg + 16 * j];
                    h[gr * 128 + cg + 16 * j] = (1.f - z_) * n_ + z_ * hold;
                }
            }
        }
    }
}

// ---------------------------------------------------------------- launch ----
extern "C" void kernel_launch(void* const* d_in, const int* in_sizes, int n_in,
                              void* d_out, int out_size, void* d_ws, size_t ws_size,
                              hipStream_t stream) {
    const float* feat = (const float*)d_in[0];
    const float* W    = (const float*)d_in[1];
    const float* b    = (const float*)d_in[2];
    const float* W_ih = (const float*)d_in[3];
    const float* W_hh = (const float*)d_in[4];
    const float* b_ih = (const float*)d_in[5];
    const float* b_hh = (const float*)d_in[6];
    const int*   src  = (const int*)d_in[7];
    const int*   dst  = (const int*)d_in[8];

    float* h  = (float*)d_out;                     // [N,128]
    float* hw = (float*)d_ws;                      // [N,128]
    float* a  = hw + (size_t)N_NODES * 128;        // [N,128]

    const int elem_blocks = (N_NODES * 32 + 255) / 256;
    const int gemm_blocks = (N_NODES + 63) / 64;
    const int scat_blocks = (N_EDGES * 32 + 255) / 256;

    init_h_kernel<<<elem_blocks, 256, 0, stream>>>(feat, h);
    for (int s = 0; s < 3; ++s) {
        zero_a_kernel<<<elem_blocks, 256, 0, stream>>>(a);
        gemm_hw_kernel<<<gemm_blocks, 256, 0, stream>>>(h, W, hw);
        scatter_kernel<<<scat_blocks, 256, 0, stream>>>(hw, b, src, dst, a);
        gru_kernel<<<gemm_blocks, 256, 0, stream>>>(a, W_ih, W_hh, b_ih, b_hh, h);
    }
}

// Round 2
// 4707.318 us; speedup vs baseline: 2.6520x; 2.6520x over previous
//
#include <hip/hip_runtime.h>
#include <math.h>

#define N_NODES 100000
#define N_EDGES 1600000
#define H 128
#define F 64

__device__ inline unsigned short f32_to_bf16(float x) {
    unsigned u = __float_as_uint(x);
    unsigned r = u + 0x7fff + ((u >> 16) & 1);   // RNE
    return (unsigned short)(r >> 16);
}

// ---------------------------------------------------------------- init h ----
__global__ __launch_bounds__(256) void init_h_kernel(const float* __restrict__ f,
                                                     float* __restrict__ h) {
    int idx = blockIdx.x * 256 + threadIdx.x;          // over N*32 float4
    if (idx >= N_NODES * 32) return;
    int r = idx >> 5, c4 = idx & 31;
    float4 v = make_float4(0.f, 0.f, 0.f, 0.f);
    if (c4 < 16) v = ((const float4*)f)[r * 16 + c4];
    ((float4*)h)[idx] = v;
}

// ---------------------------------------------------------------- CSR build -
__global__ __launch_bounds__(256) void hist_kernel(const int* __restrict__ dst,
                                                   int* __restrict__ cnt) {
    int e = blockIdx.x * 256 + threadIdx.x;
    if (e < N_EDGES) atomicAdd(&cnt[dst[e]], 1);
}

__global__ __launch_bounds__(1024) void scanA_kernel(const int* __restrict__ cnt,
                                                     int* __restrict__ tmp_incl,
                                                     int* __restrict__ blocksum) {
    __shared__ int sm[1024];
    int i = blockIdx.x * 1024 + threadIdx.x;
    int v = (i < N_NODES) ? cnt[i] : 0;
    sm[threadIdx.x] = v;
    __syncthreads();
    for (int off = 1; off < 1024; off <<= 1) {
        int t = (threadIdx.x >= off) ? sm[threadIdx.x - off] : 0;
        __syncthreads();
        sm[threadIdx.x] += t;
        __syncthreads();
    }
    if (i < N_NODES) tmp_incl[i] = sm[threadIdx.x];
    if (threadIdx.x == 1023) blocksum[blockIdx.x] = sm[1023];
}

__global__ __launch_bounds__(128) void scanB_kernel(const int* __restrict__ blocksum,
                                                    int* __restrict__ blockoff, int nb) {
    __shared__ int sm[128];
    int v = (threadIdx.x < nb) ? blocksum[threadIdx.x] : 0;
    sm[threadIdx.x] = v;
    __syncthreads();
    for (int off = 1; off < 128; off <<= 1) {
        int t = (threadIdx.x >= off) ? sm[threadIdx.x - off] : 0;
        __syncthreads();
        sm[threadIdx.x] += t;
        __syncthreads();
    }
    if (threadIdx.x < nb) blockoff[threadIdx.x] = sm[threadIdx.x] - v;  // exclusive
}

__global__ __launch_bounds__(256) void scanC_kernel(const int* __restrict__ tmp_incl,
                                                    const int* __restrict__ blockoff,
                                                    int* __restrict__ cnt_cursor,
                                                    int* __restrict__ row_ptr) {
    int i = blockIdx.x * 256 + threadIdx.x;
    if (i >= N_NODES) return;
    int incl = tmp_incl[i] + blockoff[i >> 10];
    row_ptr[i + 1] = incl;
    cnt_cursor[i] = incl - cnt_cursor[i];     // exclusive prefix -> fill cursor
    if (i == 0) row_ptr[0] = 0;
}

__global__ __launch_bounds__(256) void fill_kernel(const int* __restrict__ src,
                                                   const int* __restrict__ dst,
                                                   int* __restrict__ cursor,
                                                   int* __restrict__ csr_src) {
    int e = blockIdx.x * 256 + threadIdx.x;
    if (e >= N_EDGES) return;
    int pos = atomicAdd(&cursor[dst[e]], 1);
    csr_src[pos] = src[e];
}

// ---------------------------------------------------------------- hw GEMM ---
// hw(bf16) = h @ W.T      [N,128] x [128,128]
__global__ __launch_bounds__(256, 2) void gemm_hw_kernel(const float* __restrict__ h,
                                                         const float* __restrict__ W,
                                                         unsigned short* __restrict__ hw) {
    __shared__ float As[64][132];
    __shared__ float Ws[128][36];
    const int tid = threadIdx.x;
    const int row0 = blockIdx.x * 64;
    const int cg = tid & 15, rg = tid >> 4;

#pragma unroll
    for (int i = 0; i < 8; ++i) {
        int idx = tid + 256 * i;
        int r = idx >> 5, c4 = idx & 31;
        int gr = row0 + r; if (gr >= N_NODES) gr = N_NODES - 1;
        *(float4*)&As[r][c4 * 4] = ((const float4*)h)[gr * 32 + c4];
    }

    float acc[4][8] = {};
    for (int kc = 0; kc < 4; ++kc) {
        __syncthreads();
#pragma unroll
        for (int i = 0; i < 4; ++i) {
            int idx = tid + 256 * i;
            int c = idx >> 3, k4 = idx & 7;
            *(float4*)&Ws[c][k4 * 4] = ((const float4*)W)[c * 32 + kc * 8 + k4];
        }
        __syncthreads();
#pragma unroll
        for (int k = 0; k < 32; ++k) {
            float av[4], wv[8];
#pragma unroll
            for (int i = 0; i < 4; ++i) av[i] = As[rg + 16 * i][kc * 32 + k];
#pragma unroll
            for (int j = 0; j < 8; ++j) wv[j] = Ws[cg + 16 * j][k];
#pragma unroll
            for (int i = 0; i < 4; ++i)
#pragma unroll
                for (int j = 0; j < 8; ++j) acc[i][j] += av[i] * wv[j];
        }
    }
#pragma unroll
    for (int i = 0; i < 4; ++i) {
        int gr = row0 + rg + 16 * i;
        if (gr < N_NODES) {
#pragma unroll
            for (int j = 0; j < 8; ++j)
                hw[gr * 128 + cg + 16 * j] = f32_to_bf16(acc[i][j]);
        }
    }
}

// ---------------------------------------------------------------- gather ----
// a[n] = sum_{e in in(n)} hw[src[e]] + deg(n)*b     one wave per node.
__global__ __launch_bounds__(256) void gather_kernel(const unsigned int* __restrict__ hw,
                                                     const float* __restrict__ b,
                                                     const int* __restrict__ row_ptr,
                                                     const int* __restrict__ csr_src,
                                                     float* __restrict__ a) {
    int node = blockIdx.x * 4 + (threadIdx.x >> 6);
    if (node >= N_NODES) return;
    int lane = threadIdx.x & 63;
    int beg = row_ptr[node], end = row_ptr[node + 1];
    float acc0 = 0.f, acc1 = 0.f;
    int i = beg;
    for (; i + 1 < end; i += 2) {
        int s0 = csr_src[i], s1 = csr_src[i + 1];
        unsigned u0 = hw[(size_t)s0 * 64 + lane];
        unsigned u1 = hw[(size_t)s1 * 64 + lane];
        acc0 += __uint_as_float(u0 << 16);
        acc1 += __uint_as_float(u0 & 0xffff0000u);
        acc0 += __uint_as_float(u1 << 16);
        acc1 += __uint_as_float(u1 & 0xffff0000u);
    }
    if (i < end) {
        int s0 = csr_src[i];
        unsigned u0 = hw[(size_t)s0 * 64 + lane];
        acc0 += __uint_as_float(u0 << 16);
        acc1 += __uint_as_float(u0 & 0xffff0000u);
    }
    float deg = (float)(end - beg);
    float2 bb = ((const float2*)b)[lane];
    float2 out;
    out.x = acc0 + deg * bb.x;
    out.y = acc1 + deg * bb.y;
    ((float2*)a)[(size_t)node * 64 + lane] = out;
}

// ---------------------------------------------------------------- GRU -------
__global__ __launch_bounds__(256, 2) void gru_kernel(const float* __restrict__ a,
                                                     const float* __restrict__ W_ih,
                                                     const float* __restrict__ W_hh,
                                                     const float* __restrict__ b_ih,
                                                     const float* __restrict__ b_hh,
                                                     float* __restrict__ h) {
    __shared__ float As[64][132];
    __shared__ float Ws[128][36];
    const int tid = threadIdx.x;
    const int row0 = blockIdx.x * 64;
    const int cg = tid & 15, rg = tid >> 4;

#pragma unroll
    for (int i = 0; i < 8; ++i) {
        int idx = tid + 256 * i;
        int r = idx >> 5, c4 = idx & 31;
        int gr = row0 + r; if (gr >= N_NODES) gr = N_NODES - 1;
        *(float4*)&As[r][c4 * 4] = ((const float4*)a)[gr * 32 + c4];
    }

    float gi[3][4][8] = {};
    for (int g = 0; g < 3; ++g) {
        for (int kc = 0; kc < 4; ++kc) {
            __syncthreads();
#pragma unroll
            for (int i = 0; i < 4; ++i) {
                int idx = tid + 256 * i;
                int c = idx >> 3, k4 = idx & 7;
                *(float4*)&Ws[c][k4 * 4] =
                    ((const float4*)W_ih)[(g * 128 + c) * 32 + kc * 8 + k4];
            }
            __syncthreads();
#pragma unroll
            for (int k = 0; k < 32; ++k) {
                float av[4], wv[8];
#pragma unroll
                for (int i = 0; i < 4; ++i) av[i] = As[rg + 16 * i][kc * 32 + k];
#pragma unroll
                for (int j = 0; j < 8; ++j) wv[j] = Ws[cg + 16 * j][k];
#pragma unroll
                for (int i = 0; i < 4; ++i)
#pragma unroll
                    for (int j = 0; j < 8; ++j) gi[g][i][j] += av[i] * wv[j];
            }
        }
    }

    __syncthreads();
#pragma unroll
    for (int i = 0; i < 8; ++i) {
        int idx = tid + 256 * i;
        int r = idx >> 5, c4 = idx & 31;
        int gr = row0 + r; if (gr >= N_NODES) gr = N_NODES - 1;
        *(float4*)&As[r][c4 * 4] = ((const float4*)h)[gr * 32 + c4];
    }

    for (int g = 0; g < 3; ++g) {
        float gh[4][8] = {};
        for (int kc = 0; kc < 4; ++kc) {
            __syncthreads();
#pragma unroll
            for (int i = 0; i < 4; ++i) {
                int idx = tid + 256 * i;
                int c = idx >> 3, k4 = idx & 7;
                *(float4*)&Ws[c][k4 * 4] =
                    ((const float4*)W_hh)[(g * 128 + c) * 32 + kc * 8 + k4];
            }
            __syncthreads();
#pragma unroll
            for (int k = 0; k < 32; ++k) {
                float av[4], wv[8];
#pragma unroll
                for (int i = 0; i < 4; ++i) av[i] = As[rg + 16 * i][kc * 32 + k];
#pragma unroll
                for (int j = 0; j < 8; ++j) wv[j] = Ws[cg + 16 * j][k];
#pragma unroll
                for (int i = 0; i < 4; ++i)
#pragma unroll
                    for (int j = 0; j < 8; ++j) gh[i][j] += av[i] * wv[j];
            }
        }
        float bih[8], bhh[8];
#pragma unroll
        for (int j = 0; j < 8; ++j) {
            bih[j] = b_ih[g * 128 + cg + 16 * j];
            bhh[j] = b_hh[g * 128 + cg + 16 * j];
        }
        if (g == 0 || g == 1) {
#pragma unroll
            for (int i = 0; i < 4; ++i)
#pragma unroll
                for (int j = 0; j < 8; ++j) {
                    float x = gi[g][i][j] + bih[j] + gh[i][j] + bhh[j];
                    gi[g][i][j] = 1.f / (1.f + __expf(-x));
                }
        } else {
#pragma unroll
            for (int i = 0; i < 4; ++i) {
                int gr = row0 + rg + 16 * i;
                if (gr >= N_NODES) continue;
#pragma unroll
                for (int j = 0; j < 8; ++j) {
                    float r_ = gi[0][i][j];
                    float z_ = gi[1][i][j];
                    float n_ = tanhf(gi[2][i][j] + bih[j] + r_ * (gh[i][j] + bhh[j]));
                    float hold = As[rg + 16 * i][cg + 16 * j];
                    h[gr * 128 + cg + 16 * j] = (1.f - z_) * n_ + z_ * hold;
                }
            }
        }
    }
}

// ---------------------------------------------------------------- launch ----
extern "C" void kernel_launch(void* const* d_in, const int* in_sizes, int n_in,
                              void* d_out, int out_size, void* d_ws, size_t ws_size,
                              hipStream_t stream) {
    const float* feat = (const float*)d_in[0];
    const float* W    = (const float*)d_in[1];
    const float* b    = (const float*)d_in[2];
    const float* W_ih = (const float*)d_in[3];
    const float* W_hh = (const float*)d_in[4];
    const float* b_ih = (const float*)d_in[5];
    const float* b_hh = (const float*)d_in[6];
    const int*   src  = (const int*)d_in[7];
    const int*   dst  = (const int*)d_in[8];

    float* h = (float*)d_out;                              // [N,128]

    char* w = (char*)d_ws;
    float*          a        = (float*)w;          w += (size_t)N_NODES * 128 * 4;  // 51.2 MB
    unsigned short* hw       = (unsigned short*)w; w += (size_t)N_NODES * 128 * 2;  // 25.6 MB
    int*            csr_src  = (int*)w;            w += (size_t)N_EDGES * 4;        // 6.4 MB
    int*            tmp_incl = (int*)w;            w += (size_t)N_NODES * 4;
    int*            row_ptr  = (int*)w;            w += ((size_t)N_NODES + 4) * 4;
    int*            cnt      = (int*)w;            w += (size_t)N_NODES * 4;        // counts -> cursor
    int*            blocksum = (int*)w;            w += 128 * 4;
    int*            blockoff = (int*)w;

    const int elem_blocks = (N_NODES * 32 + 255) / 256;
    const int gemm_blocks = (N_NODES + 63) / 64;
    const int edge_blocks = (N_EDGES + 255) / 256;
    const int node_blocks = (N_NODES + 255) / 256;
    const int scanA_blocks = (N_NODES + 1023) / 1024;      // 98
    const int gath_blocks = (N_NODES + 3) / 4;

    init_h_kernel<<<elem_blocks, 256, 0, stream>>>(feat, h);

    // ---- CSR by dst (graph static across the 3 steps: build once per call)
    hipMemsetAsync(cnt, 0, (size_t)N_NODES * 4, stream);
    hist_kernel<<<edge_blocks, 256, 0, stream>>>(dst, cnt);
    scanA_kernel<<<scanA_blocks, 1024, 0, stream>>>(cnt, tmp_incl, blocksum);
    scanB_kernel<<<1, 128, 0, stream>>>(blocksum, blockoff, scanA_blocks);
    scanC_kernel<<<node_blocks, 256, 0, stream>>>(tmp_incl, blockoff, cnt, row_ptr);
    fill_kernel<<<edge_blocks, 256, 0, stream>>>(src, dst, cnt, csr_src);

    for (int s = 0; s < 3; ++s) {
        gemm_hw_kernel<<<gemm_blocks, 256, 0, stream>>>(h, W, hw);
        gather_kernel<<<gath_blocks, 256, 0, stream>>>((const unsigned int*)hw, b,
                                                       row_ptr, csr_src, a);
        gru_kernel<<<gemm_blocks, 256, 0, stream>>>(a, W_ih, W_hh, b_ih, b_hh, h);
    }
}

// Round 4
// 1215.508 us; speedup vs baseline: 10.2706x; 3.8727x over previous
//
#include <hip/hip_runtime.h>
#include <math.h>

#define N_NODES 100000
#define N_EDGES 1600000

typedef __attribute__((ext_vector_type(8))) short short8;
typedef __attribute__((ext_vector_type(4))) float f32x4;

__device__ inline unsigned short f32_to_bf16(float x) {
    unsigned u = __float_as_uint(x);
    unsigned r = u + 0x7fff + ((u >> 16) & 1);   // RNE
    return (unsigned short)(r >> 16);
}
__device__ inline float bf16_to_f32(unsigned short u) {
    return __uint_as_float(((unsigned)u) << 16);
}

// Split 8 consecutive f32 into hi/lo bf16 fragments: x ~= hi + lo (residual ~2^-17|x|)
__device__ inline void split8(const float* __restrict__ p, short8& hi, short8& lo) {
    float4 v0 = ((const float4*)p)[0];
    float4 v1 = ((const float4*)p)[1];
    float xs[8] = {v0.x, v0.y, v0.z, v0.w, v1.x, v1.y, v1.z, v1.w};
#pragma unroll
    for (int j = 0; j < 8; ++j) {
        unsigned short hbits = f32_to_bf16(xs[j]);
        float r = xs[j] - bf16_to_f32(hbits);
        hi[j] = (short)hbits;
        lo[j] = (short)f32_to_bf16(r);
    }
}

// ---------------------------------------------------------------- cvt -------
__global__ __launch_bounds__(256) void cvt_bf16_kernel(const float* __restrict__ in,
                                                       unsigned short* __restrict__ out,
                                                       int n) {
    int i = blockIdx.x * 256 + threadIdx.x;
    if (i < n) out[i] = f32_to_bf16(in[i]);
}

// ---------------------------------------------------------------- init h ----
__global__ __launch_bounds__(256) void init_h_kernel(const float* __restrict__ f,
                                                     float* __restrict__ h) {
    int idx = blockIdx.x * 256 + threadIdx.x;          // over N*32 float4
    if (idx >= N_NODES * 32) return;
    int r = idx >> 5, c4 = idx & 31;
    float4 v = make_float4(0.f, 0.f, 0.f, 0.f);
    if (c4 < 16) v = ((const float4*)f)[r * 16 + c4];
    ((float4*)h)[idx] = v;
}

// ---------------------------------------------------------------- CSR build -
__global__ __launch_bounds__(256) void hist_kernel(const int* __restrict__ dst,
                                                   int* __restrict__ cnt) {
    int e = blockIdx.x * 256 + threadIdx.x;
    if (e < N_EDGES) atomicAdd(&cnt[dst[e]], 1);
}

__global__ __launch_bounds__(1024) void scanA_kernel(const int* __restrict__ cnt,
                                                     int* __restrict__ tmp_incl,
                                                     int* __restrict__ blocksum) {
    __shared__ int sm[1024];
    int i = blockIdx.x * 1024 + threadIdx.x;
    int v = (i < N_NODES) ? cnt[i] : 0;
    sm[threadIdx.x] = v;
    __syncthreads();
    for (int off = 1; off < 1024; off <<= 1) {
        int t = (threadIdx.x >= off) ? sm[threadIdx.x - off] : 0;
        __syncthreads();
        sm[threadIdx.x] += t;
        __syncthreads();
    }
    if (i < N_NODES) tmp_incl[i] = sm[threadIdx.x];
    if (threadIdx.x == 1023) blocksum[blockIdx.x] = sm[1023];
}

__global__ __launch_bounds__(128) void scanB_kernel(const int* __restrict__ blocksum,
                                                    int* __restrict__ blockoff, int nb) {
    __shared__ int sm[128];
    int v = (threadIdx.x < nb) ? blocksum[threadIdx.x] : 0;
    sm[threadIdx.x] = v;
    __syncthreads();
    for (int off = 1; off < 128; off <<= 1) {
        int t = (threadIdx.x >= off) ? sm[threadIdx.x - off] : 0;
        __syncthreads();
        sm[threadIdx.x] += t;
        __syncthreads();
    }
    if (threadIdx.x < nb) blockoff[threadIdx.x] = sm[threadIdx.x] - v;  // exclusive
}

__global__ __launch_bounds__(256) void scanC_kernel(const int* __restrict__ tmp_incl,
                                                    const int* __restrict__ blockoff,
                                                    int* __restrict__ cnt_cursor,
                                                    int* __restrict__ row_ptr) {
    int i = blockIdx.x * 256 + threadIdx.x;
    if (i >= N_NODES) return;
    int incl = tmp_incl[i] + blockoff[i >> 10];
    row_ptr[i + 1] = incl;
    cnt_cursor[i] = incl - cnt_cursor[i];     // exclusive prefix -> fill cursor
    if (i == 0) row_ptr[0] = 0;
}

__global__ __launch_bounds__(256) void fill_kernel(const int* __restrict__ src,
                                                   const int* __restrict__ dst,
                                                   int* __restrict__ cursor,
                                                   int* __restrict__ csr_src) {
    int e = blockIdx.x * 256 + threadIdx.x;
    if (e >= N_EDGES) return;
    int pos = atomicAdd(&cursor[dst[e]], 1);
    csr_src[pos] = src[e];
}

// ---------------------------------------------------------------- hw GEMM ---
// hw(bf16) = h(f32, split hi/lo) @ Wb(bf16).T    MFMA, no LDS.
// Block = 16 nodes; wave w owns cols w*32..w*32+31.
__global__ __launch_bounds__(256) void gemm_hw_kernel(const float* __restrict__ h,
                                                      const unsigned short* __restrict__ Wb,
                                                      unsigned short* __restrict__ hw) {
    const int lane = threadIdx.x & 63;
    const int w    = threadIdx.x >> 6;
    const int l15  = lane & 15, hi = lane >> 4;
    const int n0   = blockIdx.x * 16;

    f32x4 acc0 = {0.f, 0.f, 0.f, 0.f};
    f32x4 acc1 = {0.f, 0.f, 0.f, 0.f};
#pragma unroll
    for (int k0 = 0; k0 < 128; k0 += 32) {
        short8 ah, al;
        split8(&h[(size_t)(n0 + l15) * 128 + k0 + hi * 8], ah, al);
        short8 b0 = *(const short8*)&Wb[(size_t)(w * 32 + l15) * 128 + k0 + hi * 8];
        short8 b1 = *(const short8*)&Wb[(size_t)(w * 32 + 16 + l15) * 128 + k0 + hi * 8];
        acc0 = __builtin_amdgcn_mfma_f32_16x16x32_bf16(ah, b0, acc0, 0, 0, 0);
        acc0 = __builtin_amdgcn_mfma_f32_16x16x32_bf16(al, b0, acc0, 0, 0, 0);
        acc1 = __builtin_amdgcn_mfma_f32_16x16x32_bf16(ah, b1, acc1, 0, 0, 0);
        acc1 = __builtin_amdgcn_mfma_f32_16x16x32_bf16(al, b1, acc1, 0, 0, 0);
    }
#pragma unroll
    for (int r = 0; r < 4; ++r) {
        int row = n0 + hi * 4 + r;
        hw[(size_t)row * 128 + w * 32 + l15]      = f32_to_bf16(acc0[r]);
        hw[(size_t)row * 128 + w * 32 + 16 + l15] = f32_to_bf16(acc1[r]);
    }
}

// ---------------------------------------------------------------- gather ----
// a_f32[n] = sum_{e in in(n)} hw[src[e]] + deg(n)*b     one wave per node.
__global__ __launch_bounds__(256) void gather_kernel(const unsigned int* __restrict__ hw,
                                                     const float* __restrict__ b,
                                                     const int* __restrict__ row_ptr,
                                                     const int* __restrict__ csr_src,
                                                     float* __restrict__ a) {
    int node = blockIdx.x * 4 + (threadIdx.x >> 6);
    if (node >= N_NODES) return;
    int lane = threadIdx.x & 63;
    int beg = row_ptr[node], end = row_ptr[node + 1];
    float acc0 = 0.f, acc1 = 0.f;
    int i = beg;
    for (; i + 1 < end; i += 2) {
        int s0 = csr_src[i], s1 = csr_src[i + 1];
        unsigned u0 = hw[(size_t)s0 * 64 + lane];
        unsigned u1 = hw[(size_t)s1 * 64 + lane];
        acc0 += __uint_as_float(u0 << 16);
        acc1 += __uint_as_float(u0 & 0xffff0000u);
        acc0 += __uint_as_float(u1 << 16);
        acc1 += __uint_as_float(u1 & 0xffff0000u);
    }
    if (i < end) {
        int s0 = csr_src[i];
        unsigned u0 = hw[(size_t)s0 * 64 + lane];
        acc0 += __uint_as_float(u0 << 16);
        acc1 += __uint_as_float(u0 & 0xffff0000u);
    }
    float deg = (float)(end - beg);
    float2 bb = ((const float2*)b)[lane];
    float2 o;
    o.x = acc0 + deg * bb.x;
    o.y = acc1 + deg * bb.y;
    ((float2*)a)[(size_t)node * 64 + lane] = o;
}

// ---------------------------------------------------------------- GRU -------
// gi = a(f32,split)@W_ih^T, gh = h(f32,split)@W_hh^T (MFMA, no LDS), gates, h.
// Block = 16 nodes; wave w owns cols w*32..w*32+31 of EVERY gate.
__global__ __launch_bounds__(256) void gru_kernel(const float* __restrict__ a,
                                                  const unsigned short* __restrict__ Wihb,
                                                  const unsigned short* __restrict__ Whhb,
                                                  const float* __restrict__ b_ih,
                                                  const float* __restrict__ b_hh,
                                                  float* h) {
    const int lane = threadIdx.x & 63;
    const int w    = threadIdx.x >> 6;
    const int l15  = lane & 15, hi = lane >> 4;
    const int n0   = blockIdx.x * 16;
    const int cw   = w * 32;

    f32x4 z1[3][2];
    f32x4 z2[3][2];
#pragma unroll
    for (int g = 0; g < 3; ++g)
#pragma unroll
        for (int t = 0; t < 2; ++t) {
            z1[g][t] = (f32x4){0.f, 0.f, 0.f, 0.f};
            z2[g][t] = (f32x4){0.f, 0.f, 0.f, 0.f};
        }

#pragma unroll
    for (int k0 = 0; k0 < 128; k0 += 32) {
        short8 ah, al, hh, hl;
        split8(&a[(size_t)(n0 + l15) * 128 + k0 + hi * 8], ah, al);
        split8(&h[(size_t)(n0 + l15) * 128 + k0 + hi * 8], hh, hl);
#pragma unroll
        for (int g = 0; g < 3; ++g) {
#pragma unroll
            for (int t = 0; t < 2; ++t) {
                int wrow = g * 128 + cw + t * 16 + l15;
                short8 wi = *(const short8*)&Wihb[(size_t)wrow * 128 + k0 + hi * 8];
                z1[g][t] = __builtin_amdgcn_mfma_f32_16x16x32_bf16(ah, wi, z1[g][t], 0, 0, 0);
                z1[g][t] = __builtin_amdgcn_mfma_f32_16x16x32_bf16(al, wi, z1[g][t], 0, 0, 0);
                short8 wh = *(const short8*)&Whhb[(size_t)wrow * 128 + k0 + hi * 8];
                z2[g][t] = __builtin_amdgcn_mfma_f32_16x16x32_bf16(hh, wh, z2[g][t], 0, 0, 0);
                z2[g][t] = __builtin_amdgcn_mfma_f32_16x16x32_bf16(hl, wh, z2[g][t], 0, 0, 0);
            }
        }
    }

#pragma unroll
    for (int t = 0; t < 2; ++t) {
        int c = cw + t * 16 + l15;
        float bir = b_ih[c], biz = b_ih[128 + c], bin = b_ih[256 + c];
        float bhr = b_hh[c], bhz = b_hh[128 + c], bhn = b_hh[256 + c];
#pragma unroll
        for (int r = 0; r < 4; ++r) {
            int row = n0 + hi * 4 + r;
            float hold = h[(size_t)row * 128 + c];
            float rr = 1.f / (1.f + __expf(-(z1[0][t][r] + bir + z2[0][t][r] + bhr)));
            float zz = 1.f / (1.f + __expf(-(z1[1][t][r] + biz + z2[1][t][r] + bhz)));
            float nn = tanhf(z1[2][t][r] + bin + rr * (z2[2][t][r] + bhn));
            h[(size_t)row * 128 + c] = (1.f - zz) * nn + zz * hold;
        }
    }
}

// ---------------------------------------------------------------- launch ----
extern "C" void kernel_launch(void* const* d_in, const int* in_sizes, int n_in,
                              void* d_out, int out_size, void* d_ws, size_t ws_size,
                              hipStream_t stream) {
    const float* feat = (const float*)d_in[0];
    const float* W    = (const float*)d_in[1];
    const float* b    = (const float*)d_in[2];
    const float* W_ih = (const float*)d_in[3];
    const float* W_hh = (const float*)d_in[4];
    const float* b_ih = (const float*)d_in[5];
    const float* b_hh = (const float*)d_in[6];
    const int*   src  = (const int*)d_in[7];
    const int*   dst  = (const int*)d_in[8];

    float* h = (float*)d_out;                              // [N,128] f32

    char* w = (char*)d_ws;
    float*          a        = (float*)w;          w += (size_t)N_NODES * 128 * 4;  // f32
    unsigned short* hwb      = (unsigned short*)w; w += (size_t)N_NODES * 128 * 2;  // bf16
    unsigned short* Wb       = (unsigned short*)w; w += (size_t)128 * 128 * 2;
    unsigned short* Wihb     = (unsigned short*)w; w += (size_t)384 * 128 * 2;
    unsigned short* Whhb     = (unsigned short*)w; w += (size_t)384 * 128 * 2;
    int*            csr_src  = (int*)w;            w += (size_t)N_EDGES * 4;
    int*            tmp_incl = (int*)w;            w += (size_t)N_NODES * 4;
    int*            row_ptr  = (int*)w;            w += ((size_t)N_NODES + 4) * 4;
    int*            cnt      = (int*)w;            w += (size_t)N_NODES * 4;
    int*            blocksum = (int*)w;            w += 128 * 4;
    int*            blockoff = (int*)w;

    const int elem_blocks  = (N_NODES * 32 + 255) / 256;
    const int tile_blocks  = N_NODES / 16;                 // 6250 (exact)
    const int edge_blocks  = (N_EDGES + 255) / 256;
    const int node_blocks  = (N_NODES + 255) / 256;
    const int scanA_blocks = (N_NODES + 1023) / 1024;      // 98
    const int gath_blocks  = (N_NODES + 3) / 4;

    init_h_kernel<<<elem_blocks, 256, 0, stream>>>(feat, h);
    cvt_bf16_kernel<<<(128 * 128 + 255) / 256, 256, 0, stream>>>(W, Wb, 128 * 128);
    cvt_bf16_kernel<<<(384 * 128 + 255) / 256, 256, 0, stream>>>(W_ih, Wihb, 384 * 128);
    cvt_bf16_kernel<<<(384 * 128 + 255) / 256, 256, 0, stream>>>(W_hh, Whhb, 384 * 128);

    // ---- CSR by dst (graph static across the 3 steps)
    hipMemsetAsync(cnt, 0, (size_t)N_NODES * 4, stream);
    hist_kernel<<<edge_blocks, 256, 0, stream>>>(dst, cnt);
    scanA_kernel<<<scanA_blocks, 1024, 0, stream>>>(cnt, tmp_incl, blocksum);
    scanB_kernel<<<1, 128, 0, stream>>>(blocksum, blockoff, scanA_blocks);
    scanC_kernel<<<node_blocks, 256, 0, stream>>>(tmp_incl, blockoff, cnt, row_ptr);
    fill_kernel<<<edge_blocks, 256, 0, stream>>>(src, dst, cnt, csr_src);

    for (int s = 0; s < 3; ++s) {
        gemm_hw_kernel<<<tile_blocks, 256, 0, stream>>>(h, Wb, hwb);
        gather_kernel<<<gath_blocks, 256, 0, stream>>>((const unsigned int*)hwb, b,
                                                       row_ptr, csr_src, a);
        gru_kernel<<<tile_blocks, 256, 0, stream>>>(a, Wihb, Whhb, b_ih, b_hh, h);
    }
}

// Round 5
// 1170.249 us; speedup vs baseline: 10.6678x; 1.0387x over previous
//
#include <hip/hip_runtime.h>
#include <math.h>

#define N_NODES 100000
#define N_EDGES 1600000

typedef __attribute__((ext_vector_type(8))) short short8;
typedef __attribute__((ext_vector_type(4))) float f32x4;

__device__ inline unsigned short f32_to_bf16(float x) {
    unsigned u = __float_as_uint(x);
    unsigned r = u + 0x7fff + ((u >> 16) & 1);   // RNE
    return (unsigned short)(r >> 16);
}
__device__ inline float bf16_to_f32(unsigned short u) {
    return __uint_as_float(((unsigned)u) << 16);
}
__device__ inline void split1(float x, unsigned short& hi, unsigned short& lo) {
    hi = f32_to_bf16(x);
    lo = f32_to_bf16(x - bf16_to_f32(hi));
}

// ---------------------------------------------------------------- cvt -------
__global__ __launch_bounds__(256) void cvt_bf16_kernel(const float* __restrict__ in,
                                                       unsigned short* __restrict__ out,
                                                       int n) {
    int i = blockIdx.x * 256 + threadIdx.x;
    if (i < n) out[i] = f32_to_bf16(in[i]);
}

// ---------------------------------------------------------------- init h ----
// h = [features | 0] stored as split bf16 pair (hi,lo).
__global__ __launch_bounds__(256) void init_h_kernel(const float* __restrict__ f,
                                                     unsigned short* __restrict__ h_hi,
                                                     unsigned short* __restrict__ h_lo) {
    int idx = blockIdx.x * 256 + threadIdx.x;          // over N*32 float4
    if (idx >= N_NODES * 32) return;
    int r = idx >> 5, c4 = idx & 31;
    float4 v = make_float4(0.f, 0.f, 0.f, 0.f);
    if (c4 < 16) v = ((const float4*)f)[r * 16 + c4];
    ushort4 hv, lv;
    split1(v.x, hv.x, lv.x); split1(v.y, hv.y, lv.y);
    split1(v.z, hv.z, lv.z); split1(v.w, hv.w, lv.w);
    ((ushort4*)h_hi)[idx] = hv;
    ((ushort4*)h_lo)[idx] = lv;
}

// ---------------------------------------------------------------- CSR build -
__global__ __launch_bounds__(256) void hist_kernel(const int* __restrict__ dst,
                                                   int* __restrict__ cnt) {
    int e = blockIdx.x * 256 + threadIdx.x;
    if (e < N_EDGES) atomicAdd(&cnt[dst[e]], 1);
}

__global__ __launch_bounds__(1024) void scanA_kernel(const int* __restrict__ cnt,
                                                     int* __restrict__ row_ptr,
                                                     int* __restrict__ blocksum) {
    __shared__ int sm[1024];
    int i = blockIdx.x * 1024 + threadIdx.x;
    int v = (i < N_NODES) ? cnt[i] : 0;
    sm[threadIdx.x] = v;
    __syncthreads();
    for (int off = 1; off < 1024; off <<= 1) {
        int t = (threadIdx.x >= off) ? sm[threadIdx.x - off] : 0;
        __syncthreads();
        sm[threadIdx.x] += t;
        __syncthreads();
    }
    if (i < N_NODES) row_ptr[i + 1] = sm[threadIdx.x];   // block-local inclusive
    if (threadIdx.x == 1023) blocksum[blockIdx.x] = sm[1023];
}

__global__ __launch_bounds__(128) void scanB_kernel(const int* __restrict__ blocksum,
                                                    int* __restrict__ blockoff, int nb) {
    __shared__ int sm[128];
    int v = (threadIdx.x < nb) ? blocksum[threadIdx.x] : 0;
    sm[threadIdx.x] = v;
    __syncthreads();
    for (int off = 1; off < 128; off <<= 1) {
        int t = (threadIdx.x >= off) ? sm[threadIdx.x - off] : 0;
        __syncthreads();
        sm[threadIdx.x] += t;
        __syncthreads();
    }
    if (threadIdx.x < nb) blockoff[threadIdx.x] = sm[threadIdx.x] - v;  // exclusive
}

__global__ __launch_bounds__(256) void scanC_kernel(const int* __restrict__ blockoff,
                                                    int* __restrict__ cnt_cursor,
                                                    int* __restrict__ row_ptr) {
    int i = blockIdx.x * 256 + threadIdx.x;
    if (i >= N_NODES) return;
    int incl = row_ptr[i + 1] + blockoff[i >> 10];
    row_ptr[i + 1] = incl;
    cnt_cursor[i] = incl - cnt_cursor[i];     // exclusive prefix -> fill cursor
    if (i == 0) row_ptr[0] = 0;
}

__global__ __launch_bounds__(256) void fill_kernel(const int* __restrict__ src,
                                                   const int* __restrict__ dst,
                                                   int* __restrict__ cursor,
                                                   int* __restrict__ csr_src) {
    int e = blockIdx.x * 256 + threadIdx.x;
    if (e >= N_EDGES) return;
    int pos = atomicAdd(&cursor[dst[e]], 1);
    csr_src[pos] = src[e];
}

// ---------------------------------------------------------------- hw GEMM ---
// hw(bf16) = (h_hi+h_lo) @ Wb.T   (initial step only). Block=16 nodes, no LDS.
__global__ __launch_bounds__(256) void gemm_hw_kernel(const unsigned short* __restrict__ h_hi,
                                                      const unsigned short* __restrict__ h_lo,
                                                      const unsigned short* __restrict__ Wb,
                                                      unsigned short* __restrict__ hw) {
    const int lane = threadIdx.x & 63;
    const int w    = threadIdx.x >> 6;
    const int l15  = lane & 15, hi8 = lane >> 4;
    const int n0   = blockIdx.x * 16;
    const int cw   = w * 32;

    f32x4 acc0 = {0.f, 0.f, 0.f, 0.f};
    f32x4 acc1 = {0.f, 0.f, 0.f, 0.f};
#pragma unroll
    for (int k0 = 0; k0 < 128; k0 += 32) {
        short8 ah = *(const short8*)&h_hi[(size_t)(n0 + l15) * 128 + k0 + hi8 * 8];
        short8 al = *(const short8*)&h_lo[(size_t)(n0 + l15) * 128 + k0 + hi8 * 8];
        short8 b0 = *(const short8*)&Wb[(size_t)(cw + l15) * 128 + k0 + hi8 * 8];
        short8 b1 = *(const short8*)&Wb[(size_t)(cw + 16 + l15) * 128 + k0 + hi8 * 8];
        acc0 = __builtin_amdgcn_mfma_f32_16x16x32_bf16(ah, b0, acc0, 0, 0, 0);
        acc0 = __builtin_amdgcn_mfma_f32_16x16x32_bf16(al, b0, acc0, 0, 0, 0);
        acc1 = __builtin_amdgcn_mfma_f32_16x16x32_bf16(ah, b1, acc1, 0, 0, 0);
        acc1 = __builtin_amdgcn_mfma_f32_16x16x32_bf16(al, b1, acc1, 0, 0, 0);
    }
#pragma unroll
    for (int r = 0; r < 4; ++r) {
        int row = n0 + hi8 * 4 + r;
        hw[(size_t)row * 128 + cw + l15]      = f32_to_bf16(acc0[r]);
        hw[(size_t)row * 128 + cw + 16 + l15] = f32_to_bf16(acc1[r]);
    }
}

// ---------------------------------------------------------------- fused step -
// Per block (16 nodes, 4 waves):
//   P1 gather: a = sum_{in-edges} hw_in[src] + deg*b  -> split -> LDS
//   P2 GRU GEMMs: gi = a@Wih^T, gh = h@Whh^T (a from LDS, h from global pair)
//   P3 gates: h_new -> global h pair (+f32 out on last step) + LDS (split)
//   P4 (make_hw): hw_out = h_new @ Wb^T from LDS
#define SLDS 136   // padded LDS row stride (shorts): 16B-aligned frags, <=2-way banks
__global__ __launch_bounds__(256) void gg_step_kernel(
        const unsigned int* __restrict__ hw_in,     // [N,64] bf16x2
        const int* __restrict__ row_ptr,
        const int* __restrict__ csr_src,
        const float* __restrict__ b,
        unsigned short* __restrict__ h_hi,
        unsigned short* __restrict__ h_lo,
        const unsigned short* __restrict__ Wihb,
        const unsigned short* __restrict__ Whhb,
        const float* __restrict__ b_ih,
        const float* __restrict__ b_hh,
        const unsigned short* __restrict__ Wb,
        unsigned short* __restrict__ hw_out,
        float* __restrict__ h_out,
        int make_hw, int write_out) {
    __shared__ unsigned short s_hi[16 * SLDS];
    __shared__ unsigned short s_lo[16 * SLDS];

    const int lane = threadIdx.x & 63;
    const int w    = threadIdx.x >> 6;
    const int l15  = lane & 15, hi8 = lane >> 4;
    const int n0   = blockIdx.x * 16;
    const int cw   = w * 32;

    // ---- P1: gather (wave handles 4 nodes; lane owns cols 2*lane, 2*lane+1)
    float2 bb = ((const float2*)b)[lane];
    for (int nn = 0; nn < 4; ++nn) {
        int node = n0 + w * 4 + nn;
        int beg = row_ptr[node], end = row_ptr[node + 1];
        float a0 = 0.f, a1 = 0.f;
        int i = beg;
        for (; i + 3 < end; i += 4) {
            int s0 = csr_src[i], s1 = csr_src[i + 1];
            int s2 = csr_src[i + 2], s3 = csr_src[i + 3];
            unsigned u0 = hw_in[(size_t)s0 * 64 + lane];
            unsigned u1 = hw_in[(size_t)s1 * 64 + lane];
            unsigned u2 = hw_in[(size_t)s2 * 64 + lane];
            unsigned u3 = hw_in[(size_t)s3 * 64 + lane];
            a0 += __uint_as_float(u0 << 16) + __uint_as_float(u1 << 16);
            a1 += __uint_as_float(u0 & 0xffff0000u) + __uint_as_float(u1 & 0xffff0000u);
            a0 += __uint_as_float(u2 << 16) + __uint_as_float(u3 << 16);
            a1 += __uint_as_float(u2 & 0xffff0000u) + __uint_as_float(u3 & 0xffff0000u);
        }
        for (; i < end; ++i) {
            unsigned u0 = hw_in[(size_t)csr_src[i] * 64 + lane];
            a0 += __uint_as_float(u0 << 16);
            a1 += __uint_as_float(u0 & 0xffff0000u);
        }
        float deg = (float)(end - beg);
        a0 += deg * bb.x;
        a1 += deg * bb.y;
        unsigned short h0, l0, h1, l1;
        split1(a0, h0, l0);
        split1(a1, h1, l1);
        int row = w * 4 + nn;
        *(ushort2*)&s_hi[row * SLDS + 2 * lane] = (ushort2){h0, h1};
        *(ushort2*)&s_lo[row * SLDS + 2 * lane] = (ushort2){l0, l1};
    }
    __syncthreads();

    // ---- P2: GRU GEMMs
    f32x4 z1[3][2], z2[3][2];
#pragma unroll
    for (int g = 0; g < 3; ++g)
#pragma unroll
        for (int t = 0; t < 2; ++t) {
            z1[g][t] = (f32x4){0.f, 0.f, 0.f, 0.f};
            z2[g][t] = (f32x4){0.f, 0.f, 0.f, 0.f};
        }
#pragma unroll
    for (int k0 = 0; k0 < 128; k0 += 32) {
        short8 ah = *(const short8*)&s_hi[l15 * SLDS + k0 + hi8 * 8];
        short8 al = *(const short8*)&s_lo[l15 * SLDS + k0 + hi8 * 8];
        short8 hh = *(const short8*)&h_hi[(size_t)(n0 + l15) * 128 + k0 + hi8 * 8];
        short8 hl = *(const short8*)&h_lo[(size_t)(n0 + l15) * 128 + k0 + hi8 * 8];
#pragma unroll
        for (int g = 0; g < 3; ++g) {
#pragma unroll
            for (int t = 0; t < 2; ++t) {
                int wrow = g * 128 + cw + t * 16 + l15;
                short8 wi = *(const short8*)&Wihb[(size_t)wrow * 128 + k0 + hi8 * 8];
                z1[g][t] = __builtin_amdgcn_mfma_f32_16x16x32_bf16(ah, wi, z1[g][t], 0, 0, 0);
                z1[g][t] = __builtin_amdgcn_mfma_f32_16x16x32_bf16(al, wi, z1[g][t], 0, 0, 0);
                short8 wh = *(const short8*)&Whhb[(size_t)wrow * 128 + k0 + hi8 * 8];
                z2[g][t] = __builtin_amdgcn_mfma_f32_16x16x32_bf16(hh, wh, z2[g][t], 0, 0, 0);
                z2[g][t] = __builtin_amdgcn_mfma_f32_16x16x32_bf16(hl, wh, z2[g][t], 0, 0, 0);
            }
        }
    }
    __syncthreads();   // all P2 LDS/global-h reads done before P3 overwrites

    // ---- P3: gates + h update
#pragma unroll
    for (int t = 0; t < 2; ++t) {
        int c = cw + t * 16 + l15;
        float bir = b_ih[c], biz = b_ih[128 + c], bin = b_ih[256 + c];
        float bhr = b_hh[c], bhz = b_hh[128 + c], bhn = b_hh[256 + c];
#pragma unroll
        for (int r = 0; r < 4; ++r) {
            int lrow = hi8 * 4 + r;
            size_t gidx = (size_t)(n0 + lrow) * 128 + c;
            float hold = bf16_to_f32(h_hi[gidx]) + bf16_to_f32(h_lo[gidx]);
            float rr = 1.f / (1.f + __expf(-(z1[0][t][r] + bir + z2[0][t][r] + bhr)));
            float zz = 1.f / (1.f + __expf(-(z1[1][t][r] + biz + z2[1][t][r] + bhz)));
            float nn_ = tanhf(z1[2][t][r] + bin + rr * (z2[2][t][r] + bhn));
            float hn = (1.f - zz) * nn_ + zz * hold;
            if (write_out) h_out[gidx] = hn;
            unsigned short sh, sl;
            split1(hn, sh, sl);
            h_hi[gidx] = sh;
            h_lo[gidx] = sl;
            s_hi[lrow * SLDS + c] = sh;
            s_lo[lrow * SLDS + c] = sl;
        }
    }

    // ---- P4: produce hw for next step
    if (make_hw) {
        __syncthreads();
        f32x4 c0 = {0.f, 0.f, 0.f, 0.f};
        f32x4 c1 = {0.f, 0.f, 0.f, 0.f};
#pragma unroll
        for (int k0 = 0; k0 < 128; k0 += 32) {
            short8 xh = *(const short8*)&s_hi[l15 * SLDS + k0 + hi8 * 8];
            short8 xl = *(const short8*)&s_lo[l15 * SLDS + k0 + hi8 * 8];
            short8 b0 = *(const short8*)&Wb[(size_t)(cw + l15) * 128 + k0 + hi8 * 8];
            short8 b1 = *(const short8*)&Wb[(size_t)(cw + 16 + l15) * 128 + k0 + hi8 * 8];
            c0 = __builtin_amdgcn_mfma_f32_16x16x32_bf16(xh, b0, c0, 0, 0, 0);
            c0 = __builtin_amdgcn_mfma_f32_16x16x32_bf16(xl, b0, c0, 0, 0, 0);
            c1 = __builtin_amdgcn_mfma_f32_16x16x32_bf16(xh, b1, c1, 0, 0, 0);
            c1 = __builtin_amdgcn_mfma_f32_16x16x32_bf16(xl, b1, c1, 0, 0, 0);
        }
#pragma unroll
        for (int r = 0; r < 4; ++r) {
            int row = n0 + hi8 * 4 + r;
            hw_out[(size_t)row * 128 + cw + l15]      = f32_to_bf16(c0[r]);
            hw_out[(size_t)row * 128 + cw + 16 + l15] = f32_to_bf16(c1[r]);
        }
    }
}

// ---------------------------------------------------------------- launch ----
extern "C" void kernel_launch(void* const* d_in, const int* in_sizes, int n_in,
                              void* d_out, int out_size, void* d_ws, size_t ws_size,
                              hipStream_t stream) {
    const float* feat = (const float*)d_in[0];
    const float* W    = (const float*)d_in[1];
    const float* b    = (const float*)d_in[2];
    const float* W_ih = (const float*)d_in[3];
    const float* W_hh = (const float*)d_in[4];
    const float* b_ih = (const float*)d_in[5];
    const float* b_hh = (const float*)d_in[6];
    const int*   src  = (const int*)d_in[7];
    const int*   dst  = (const int*)d_in[8];

    float* h_out = (float*)d_out;                          // [N,128] f32

    char* w = (char*)d_ws;
    unsigned short* h_hi  = (unsigned short*)w; w += (size_t)N_NODES * 128 * 2;
    unsigned short* h_lo  = (unsigned short*)w; w += (size_t)N_NODES * 128 * 2;
    unsigned short* hwA   = (unsigned short*)w; w += (size_t)N_NODES * 128 * 2;
    unsigned short* hwB   = (unsigned short*)w; w += (size_t)N_NODES * 128 * 2;
    unsigned short* Wb    = (unsigned short*)w; w += (size_t)128 * 128 * 2;
    unsigned short* Wihb  = (unsigned short*)w; w += (size_t)384 * 128 * 2;
    unsigned short* Whhb  = (unsigned short*)w; w += (size_t)384 * 128 * 2;
    int*            csr_src  = (int*)w;         w += (size_t)N_EDGES * 4;
    int*            row_ptr  = (int*)w;         w += ((size_t)N_NODES + 4) * 4;
    int*            cnt      = (int*)w;         w += (size_t)N_NODES * 4;
    int*            blocksum = (int*)w;         w += 128 * 4;
    int*            blockoff = (int*)w;

    const int elem_blocks  = (N_NODES * 32 + 255) / 256;
    const int tile_blocks  = N_NODES / 16;                 // 6250 (exact)
    const int edge_blocks  = (N_EDGES + 255) / 256;
    const int node_blocks  = (N_NODES + 255) / 256;
    const int scanA_blocks = (N_NODES + 1023) / 1024;      // 98

    init_h_kernel<<<elem_blocks, 256, 0, stream>>>(feat, h_hi, h_lo);
    cvt_bf16_kernel<<<(128 * 128 + 255) / 256, 256, 0, stream>>>(W, Wb, 128 * 128);
    cvt_bf16_kernel<<<(384 * 128 + 255) / 256, 256, 0, stream>>>(W_ih, Wihb, 384 * 128);
    cvt_bf16_kernel<<<(384 * 128 + 255) / 256, 256, 0, stream>>>(W_hh, Whhb, 384 * 128);

    // ---- CSR by dst (graph static across the 3 steps)
    hipMemsetAsync(cnt, 0, (size_t)N_NODES * 4, stream);
    hist_kernel<<<edge_blocks, 256, 0, stream>>>(dst, cnt);
    scanA_kernel<<<scanA_blocks, 1024, 0, stream>>>(cnt, row_ptr, blocksum);
    scanB_kernel<<<1, 128, 0, stream>>>(blocksum, blockoff, scanA_blocks);
    scanC_kernel<<<node_blocks, 256, 0, stream>>>(blockoff, cnt, row_ptr);
    fill_kernel<<<edge_blocks, 256, 0, stream>>>(src, dst, cnt, csr_src);

    // ---- initial hw, then 3 fused steps (hw ping-pong)
    gemm_hw_kernel<<<tile_blocks, 256, 0, stream>>>(h_hi, h_lo, Wb, hwA);
    gg_step_kernel<<<tile_blocks, 256, 0, stream>>>((const unsigned int*)hwA, row_ptr, csr_src, b,
                                                    h_hi, h_lo, Wihb, Whhb, b_ih, b_hh,
                                                    Wb, hwB, h_out, 1, 0);
    gg_step_kernel<<<tile_blocks, 256, 0, stream>>>((const unsigned int*)hwB, row_ptr, csr_src, b,
                                                    h_hi, h_lo, Wihb, Whhb, b_ih, b_hh,
                                                    Wb, hwA, h_out, 1, 0);
    gg_step_kernel<<<tile_blocks, 256, 0, stream>>>((const unsigned int*)hwA, row_ptr, csr_src, b,
                                                    h_hi, h_lo, Wihb, Whhb, b_ih, b_hh,
                                                    Wb, hwB, h_out, 0, 1);
}

// Round 6
// 963.993 us; speedup vs baseline: 12.9503x; 1.2140x over previous
//
#include <hip/hip_runtime.h>
#include <math.h>

#define N_NODES 100000
#define N_EDGES 1600000

typedef __attribute__((ext_vector_type(8))) short short8;
typedef __attribute__((ext_vector_type(4))) float f32x4;

__device__ inline unsigned short f32_to_bf16(float x) {
    unsigned u = __float_as_uint(x);
    unsigned r = u + 0x7fff + ((u >> 16) & 1);   // RNE
    return (unsigned short)(r >> 16);
}
__device__ inline float bf16_to_f32(unsigned short u) {
    return __uint_as_float(((unsigned)u) << 16);
}
__device__ inline void split1(float x, unsigned short& hi, unsigned short& lo) {
    hi = f32_to_bf16(x);
    lo = f32_to_bf16(x - bf16_to_f32(hi));
}

// ---------------------------------------------------------------- cvt -------
__global__ __launch_bounds__(256) void cvt_bf16_kernel(const float* __restrict__ in,
                                                       unsigned short* __restrict__ out,
                                                       int n) {
    int i = blockIdx.x * 256 + threadIdx.x;
    if (i < n) out[i] = f32_to_bf16(in[i]);
}

// ---------------------------------------------------------------- init h ----
__global__ __launch_bounds__(256) void init_h_kernel(const float* __restrict__ f,
                                                     unsigned short* __restrict__ h_hi,
                                                     unsigned short* __restrict__ h_lo) {
    int idx = blockIdx.x * 256 + threadIdx.x;          // over N*32 float4
    if (idx >= N_NODES * 32) return;
    int r = idx >> 5, c4 = idx & 31;
    float4 v = make_float4(0.f, 0.f, 0.f, 0.f);
    if (c4 < 16) v = ((const float4*)f)[r * 16 + c4];
    ushort4 hv, lv;
    split1(v.x, hv.x, lv.x); split1(v.y, hv.y, lv.y);
    split1(v.z, hv.z, lv.z); split1(v.w, hv.w, lv.w);
    ((ushort4*)h_hi)[idx] = hv;
    ((ushort4*)h_lo)[idx] = lv;
}

// ---------------------------------------------------------------- finalize --
__global__ __launch_bounds__(256) void finalize_kernel(const unsigned short* __restrict__ h_hi,
                                                       const unsigned short* __restrict__ h_lo,
                                                       float* __restrict__ out) {
    int idx = blockIdx.x * 256 + threadIdx.x;          // over N*32 quads
    if (idx >= N_NODES * 32) return;
    ushort4 hv = ((const ushort4*)h_hi)[idx];
    ushort4 lv = ((const ushort4*)h_lo)[idx];
    float4 o;
    o.x = bf16_to_f32(hv.x) + bf16_to_f32(lv.x);
    o.y = bf16_to_f32(hv.y) + bf16_to_f32(lv.y);
    o.z = bf16_to_f32(hv.z) + bf16_to_f32(lv.z);
    o.w = bf16_to_f32(hv.w) + bf16_to_f32(lv.w);
    ((float4*)out)[idx] = o;
}

// ---------------------------------------------------------------- CSR build -
__global__ __launch_bounds__(256) void hist_kernel(const int* __restrict__ dst,
                                                   int* __restrict__ cnt) {
    int e = blockIdx.x * 256 + threadIdx.x;
    if (e < N_EDGES) atomicAdd(&cnt[dst[e]], 1);
}

__global__ __launch_bounds__(1024) void scanA_kernel(const int* __restrict__ cnt,
                                                     int* __restrict__ row_ptr,
                                                     int* __restrict__ blocksum) {
    __shared__ int sm[1024];
    int i = blockIdx.x * 1024 + threadIdx.x;
    int v = (i < N_NODES) ? cnt[i] : 0;
    sm[threadIdx.x] = v;
    __syncthreads();
    for (int off = 1; off < 1024; off <<= 1) {
        int t = (threadIdx.x >= off) ? sm[threadIdx.x - off] : 0;
        __syncthreads();
        sm[threadIdx.x] += t;
        __syncthreads();
    }
    if (i < N_NODES) row_ptr[i + 1] = sm[threadIdx.x];   // block-local inclusive
    if (threadIdx.x == 1023) blocksum[blockIdx.x] = sm[1023];
}

__global__ __launch_bounds__(128) void scanB_kernel(const int* __restrict__ blocksum,
                                                    int* __restrict__ blockoff, int nb) {
    __shared__ int sm[128];
    int v = (threadIdx.x < nb) ? blocksum[threadIdx.x] : 0;
    sm[threadIdx.x] = v;
    __syncthreads();
    for (int off = 1; off < 128; off <<= 1) {
        int t = (threadIdx.x >= off) ? sm[threadIdx.x - off] : 0;
        __syncthreads();
        sm[threadIdx.x] += t;
        __syncthreads();
    }
    if (threadIdx.x < nb) blockoff[threadIdx.x] = sm[threadIdx.x] - v;  // exclusive
}

__global__ __launch_bounds__(256) void scanC_kernel(const int* __restrict__ blockoff,
                                                    int* __restrict__ cnt_cursor,
                                                    int* __restrict__ row_ptr) {
    int i = blockIdx.x * 256 + threadIdx.x;
    if (i >= N_NODES) return;
    int incl = row_ptr[i + 1] + blockoff[i >> 10];
    row_ptr[i + 1] = incl;
    cnt_cursor[i] = incl - cnt_cursor[i];     // exclusive prefix -> fill cursor
    if (i == 0) row_ptr[0] = 0;
}

__global__ __launch_bounds__(256) void fill_kernel(const int* __restrict__ src,
                                                   const int* __restrict__ dst,
                                                   int* __restrict__ cursor,
                                                   int* __restrict__ csr_src) {
    int e = blockIdx.x * 256 + threadIdx.x;
    if (e >= N_EDGES) return;
    int pos = atomicAdd(&cursor[dst[e]], 1);
    csr_src[pos] = src[e];
}

// ---------------------------------------------------------------- hw GEMM ---
// hw(bf16) = (h_hi+h_lo) @ Wb.T   (initial step only). Block=16 nodes, no LDS.
__global__ __launch_bounds__(256) void gemm_hw_kernel(const unsigned short* __restrict__ h_hi,
                                                      const unsigned short* __restrict__ h_lo,
                                                      const unsigned short* __restrict__ Wb,
                                                      unsigned short* __restrict__ hw) {
    const int lane = threadIdx.x & 63;
    const int w    = threadIdx.x >> 6;
    const int l15  = lane & 15, hi8 = lane >> 4;
    const int n0   = blockIdx.x * 16;
    const int cw   = w * 32;

    f32x4 acc0 = {0.f, 0.f, 0.f, 0.f};
    f32x4 acc1 = {0.f, 0.f, 0.f, 0.f};
#pragma unroll
    for (int k0 = 0; k0 < 128; k0 += 32) {
        short8 ah = *(const short8*)&h_hi[(size_t)(n0 + l15) * 128 + k0 + hi8 * 8];
        short8 al = *(const short8*)&h_lo[(size_t)(n0 + l15) * 128 + k0 + hi8 * 8];
        short8 b0 = *(const short8*)&Wb[(size_t)(cw + l15) * 128 + k0 + hi8 * 8];
        short8 b1 = *(const short8*)&Wb[(size_t)(cw + 16 + l15) * 128 + k0 + hi8 * 8];
        acc0 = __builtin_amdgcn_mfma_f32_16x16x32_bf16(ah, b0, acc0, 0, 0, 0);
        acc0 = __builtin_amdgcn_mfma_f32_16x16x32_bf16(al, b0, acc0, 0, 0, 0);
        acc1 = __builtin_amdgcn_mfma_f32_16x16x32_bf16(ah, b1, acc1, 0, 0, 0);
        acc1 = __builtin_amdgcn_mfma_f32_16x16x32_bf16(al, b1, acc1, 0, 0, 0);
    }
#pragma unroll
    for (int r = 0; r < 4; ++r) {
        int row = n0 + hi8 * 4 + r;
        hw[(size_t)row * 128 + cw + l15]      = f32_to_bf16(acc0[r]);
        hw[(size_t)row * 128 + cw + 16 + l15] = f32_to_bf16(acc1[r]);
    }
}

// ---------------------------------------------------------------- gather ----
// a_pair[n] = split( sum_{in-edges} hw[src] + deg*b )   one wave per node.
// Tiny register footprint -> high occupancy -> LLC latency hidden by TLP.
__global__ __launch_bounds__(256) void gather_kernel(const unsigned int* __restrict__ hw,
                                                     const float* __restrict__ b,
                                                     const int* __restrict__ row_ptr,
                                                     const int* __restrict__ csr_src,
                                                     unsigned short* __restrict__ a_hi,
                                                     unsigned short* __restrict__ a_lo) {
    int node = blockIdx.x * 4 + (threadIdx.x >> 6);
    int lane = threadIdx.x & 63;
    int beg = row_ptr[node], end = row_ptr[node + 1];
    float a0 = 0.f, a1 = 0.f;
    int i = beg;
    for (; i + 3 < end; i += 4) {
        int e0 = csr_src[i], e1 = csr_src[i + 1];
        int e2 = csr_src[i + 2], e3 = csr_src[i + 3];
        unsigned u0 = hw[(size_t)e0 * 64 + lane];
        unsigned u1 = hw[(size_t)e1 * 64 + lane];
        unsigned u2 = hw[(size_t)e2 * 64 + lane];
        unsigned u3 = hw[(size_t)e3 * 64 + lane];
        a0 += __uint_as_float(u0 << 16) + __uint_as_float(u1 << 16)
            + __uint_as_float(u2 << 16) + __uint_as_float(u3 << 16);
        a1 += __uint_as_float(u0 & 0xffff0000u) + __uint_as_float(u1 & 0xffff0000u)
            + __uint_as_float(u2 & 0xffff0000u) + __uint_as_float(u3 & 0xffff0000u);
    }
    for (; i < end; ++i) {
        unsigned u0 = hw[(size_t)csr_src[i] * 64 + lane];
        a0 += __uint_as_float(u0 << 16);
        a1 += __uint_as_float(u0 & 0xffff0000u);
    }
    float deg = (float)(end - beg);
    float2 bb = ((const float2*)b)[lane];
    unsigned short h0, l0, h1, l1;
    split1(a0 + deg * bb.x, h0, l0);
    split1(a1 + deg * bb.y, h1, l1);
    ((ushort2*)a_hi)[(size_t)node * 64 + lane] = (ushort2){h0, h1};
    ((ushort2*)a_lo)[(size_t)node * 64 + lane] = (ushort2){l0, l1};
}

// ---------------------------------------------------------------- GRU fused -
// 32 nodes/block, 4 waves; wave w owns cols w*32..w*32+31 for 2 node-tiles.
// gi = a@Wih^T, gh = h@Whh^T (pre-split pairs, no VALU split), gates,
// h pair update, then hw_out = h_new @ Wb^T via LDS exchange.
#define SLDS 136   // padded LDS row stride (shorts)
__global__ __launch_bounds__(256) void gru_fused_kernel(
        const unsigned short* __restrict__ a_hi,
        const unsigned short* __restrict__ a_lo,
        unsigned short* __restrict__ h_hi,
        unsigned short* __restrict__ h_lo,
        const unsigned short* __restrict__ Wihb,
        const unsigned short* __restrict__ Whhb,
        const float* __restrict__ b_ih,
        const float* __restrict__ b_hh,
        const unsigned short* __restrict__ Wb,
        unsigned short* __restrict__ hw_out,
        int make_hw) {
    __shared__ unsigned short s_hi[32 * SLDS];
    __shared__ unsigned short s_lo[32 * SLDS];

    const int lane = threadIdx.x & 63;
    const int w    = threadIdx.x >> 6;
    const int l15  = lane & 15, hi8 = lane >> 4;
    const int n0   = blockIdx.x * 32;
    const int cw   = w * 32;

    f32x4 z1[2][3][2], z2[2][3][2];
#pragma unroll
    for (int nt = 0; nt < 2; ++nt)
#pragma unroll
        for (int g = 0; g < 3; ++g)
#pragma unroll
            for (int t = 0; t < 2; ++t) {
                z1[nt][g][t] = (f32x4){0.f, 0.f, 0.f, 0.f};
                z2[nt][g][t] = (f32x4){0.f, 0.f, 0.f, 0.f};
            }

#pragma unroll
    for (int k0 = 0; k0 < 128; k0 += 32) {
        short8 ah[2], al[2], hh_[2], hl[2];
#pragma unroll
        for (int nt = 0; nt < 2; ++nt) {
            size_t ro = (size_t)(n0 + nt * 16 + l15) * 128 + k0 + hi8 * 8;
            ah[nt]  = *(const short8*)&a_hi[ro];
            al[nt]  = *(const short8*)&a_lo[ro];
            hh_[nt] = *(const short8*)&h_hi[ro];
            hl[nt]  = *(const short8*)&h_lo[ro];
        }
#pragma unroll
        for (int g = 0; g < 3; ++g)
#pragma unroll
            for (int t = 0; t < 2; ++t) {
                size_t wro = (size_t)(g * 128 + cw + t * 16 + l15) * 128 + k0 + hi8 * 8;
                short8 wi = *(const short8*)&Wihb[wro];
                short8 wh = *(const short8*)&Whhb[wro];
#pragma unroll
                for (int nt = 0; nt < 2; ++nt) {
                    z1[nt][g][t] = __builtin_amdgcn_mfma_f32_16x16x32_bf16(ah[nt], wi, z1[nt][g][t], 0, 0, 0);
                    z1[nt][g][t] = __builtin_amdgcn_mfma_f32_16x16x32_bf16(al[nt], wi, z1[nt][g][t], 0, 0, 0);
                    z2[nt][g][t] = __builtin_amdgcn_mfma_f32_16x16x32_bf16(hh_[nt], wh, z2[nt][g][t], 0, 0, 0);
                    z2[nt][g][t] = __builtin_amdgcn_mfma_f32_16x16x32_bf16(hl[nt], wh, z2[nt][g][t], 0, 0, 0);
                }
            }
    }

    // ---- gates + h update
#pragma unroll
    for (int t = 0; t < 2; ++t) {
        int c = cw + t * 16 + l15;
        float bir = b_ih[c], biz = b_ih[128 + c], bin = b_ih[256 + c];
        float bhr = b_hh[c], bhz = b_hh[128 + c], bhn = b_hh[256 + c];
#pragma unroll
        for (int nt = 0; nt < 2; ++nt)
#pragma unroll
            for (int r = 0; r < 4; ++r) {
                int lrow = nt * 16 + hi8 * 4 + r;
                size_t gidx = (size_t)(n0 + lrow) * 128 + c;
                float hold = bf16_to_f32(h_hi[gidx]) + bf16_to_f32(h_lo[gidx]);
                float rr = 1.f / (1.f + __expf(-(z1[nt][0][t][r] + bir + z2[nt][0][t][r] + bhr)));
                float zz = 1.f / (1.f + __expf(-(z1[nt][1][t][r] + biz + z2[nt][1][t][r] + bhz)));
                float nn_ = tanhf(z1[nt][2][t][r] + bin + rr * (z2[nt][2][t][r] + bhn));
                float hn = (1.f - zz) * nn_ + zz * hold;
                unsigned short sh, sl;
                split1(hn, sh, sl);
                h_hi[gidx] = sh;
                h_lo[gidx] = sl;
                s_hi[lrow * SLDS + c] = sh;
                s_lo[lrow * SLDS + c] = sl;
            }
    }

    // ---- hw for next step
    if (make_hw) {
        __syncthreads();
#pragma unroll
        for (int nt = 0; nt < 2; ++nt) {
            f32x4 c0 = {0.f, 0.f, 0.f, 0.f};
            f32x4 c1 = {0.f, 0.f, 0.f, 0.f};
#pragma unroll
            for (int k0 = 0; k0 < 128; k0 += 32) {
                short8 xh = *(const short8*)&s_hi[(nt * 16 + l15) * SLDS + k0 + hi8 * 8];
                short8 xl = *(const short8*)&s_lo[(nt * 16 + l15) * SLDS + k0 + hi8 * 8];
                short8 b0 = *(const short8*)&Wb[(size_t)(cw + l15) * 128 + k0 + hi8 * 8];
                short8 b1 = *(const short8*)&Wb[(size_t)(cw + 16 + l15) * 128 + k0 + hi8 * 8];
                c0 = __builtin_amdgcn_mfma_f32_16x16x32_bf16(xh, b0, c0, 0, 0, 0);
                c0 = __builtin_amdgcn_mfma_f32_16x16x32_bf16(xl, b0, c0, 0, 0, 0);
                c1 = __builtin_amdgcn_mfma_f32_16x16x32_bf16(xh, b1, c1, 0, 0, 0);
                c1 = __builtin_amdgcn_mfma_f32_16x16x32_bf16(xl, b1, c1, 0, 0, 0);
            }
#pragma unroll
            for (int r = 0; r < 4; ++r) {
                int row = n0 + nt * 16 + hi8 * 4 + r;
                hw_out[(size_t)row * 128 + cw + l15]      = f32_to_bf16(c0[r]);
                hw_out[(size_t)row * 128 + cw + 16 + l15] = f32_to_bf16(c1[r]);
            }
        }
    }
}

// ---------------------------------------------------------------- launch ----
extern "C" void kernel_launch(void* const* d_in, const int* in_sizes, int n_in,
                              void* d_out, int out_size, void* d_ws, size_t ws_size,
                              hipStream_t stream) {
    const float* feat = (const float*)d_in[0];
    const float* W    = (const float*)d_in[1];
    const float* b    = (const float*)d_in[2];
    const float* W_ih = (const float*)d_in[3];
    const float* W_hh = (const float*)d_in[4];
    const float* b_ih = (const float*)d_in[5];
    const float* b_hh = (const float*)d_in[6];
    const int*   src  = (const int*)d_in[7];
    const int*   dst  = (const int*)d_in[8];

    // a-pair parks in d_out during the steps (exact fit: N*128*4 bytes);
    // finalize_kernel rewrites d_out with f32 h at the end.
    unsigned short* a_hi = (unsigned short*)d_out;
    unsigned short* a_lo = a_hi + (size_t)N_NODES * 128;

    char* w = (char*)d_ws;
    unsigned short* h_hi  = (unsigned short*)w; w += (size_t)N_NODES * 128 * 2;
    unsigned short* h_lo  = (unsigned short*)w; w += (size_t)N_NODES * 128 * 2;
    unsigned short* hw    = (unsigned short*)w; w += (size_t)N_NODES * 128 * 2;
    unsigned short* Wb    = (unsigned short*)w; w += (size_t)128 * 128 * 2;
    unsigned short* Wihb  = (unsigned short*)w; w += (size_t)384 * 128 * 2;
    unsigned short* Whhb  = (unsigned short*)w; w += (size_t)384 * 128 * 2;
    int*            csr_src  = (int*)w;         w += (size_t)N_EDGES * 4;
    int*            row_ptr  = (int*)w;         w += ((size_t)N_NODES + 4) * 4;
    int*            cnt      = (int*)w;         w += (size_t)N_NODES * 4;
    int*            blocksum = (int*)w;         w += 128 * 4;
    int*            blockoff = (int*)w;

    const int elem_blocks  = (N_NODES * 32 + 255) / 256;
    const int t16_blocks   = N_NODES / 16;                 // 6250 (exact)
    const int t32_blocks   = N_NODES / 32;                 // 3125 (exact)
    const int edge_blocks  = (N_EDGES + 255) / 256;
    const int node_blocks  = (N_NODES + 255) / 256;
    const int scanA_blocks = (N_NODES + 1023) / 1024;      // 98
    const int gath_blocks  = N_NODES / 4;                  // 25000 (exact)

    init_h_kernel<<<elem_blocks, 256, 0, stream>>>(feat, h_hi, h_lo);
    cvt_bf16_kernel<<<(128 * 128 + 255) / 256, 256, 0, stream>>>(W, Wb, 128 * 128);
    cvt_bf16_kernel<<<(384 * 128 + 255) / 256, 256, 0, stream>>>(W_ih, Wihb, 384 * 128);
    cvt_bf16_kernel<<<(384 * 128 + 255) / 256, 256, 0, stream>>>(W_hh, Whhb, 384 * 128);

    // ---- CSR by dst (graph static across the 3 steps)
    hipMemsetAsync(cnt, 0, (size_t)N_NODES * 4, stream);
    hist_kernel<<<edge_blocks, 256, 0, stream>>>(dst, cnt);
    scanA_kernel<<<scanA_blocks, 1024, 0, stream>>>(cnt, row_ptr, blocksum);
    scanB_kernel<<<1, 128, 0, stream>>>(blocksum, blockoff, scanA_blocks);
    scanC_kernel<<<node_blocks, 256, 0, stream>>>(blockoff, cnt, row_ptr);
    fill_kernel<<<edge_blocks, 256, 0, stream>>>(src, dst, cnt, csr_src);

    // ---- initial hw, then 3 steps
    gemm_hw_kernel<<<t16_blocks, 256, 0, stream>>>(h_hi, h_lo, Wb, hw);
    for (int s = 0; s < 3; ++s) {
        gather_kernel<<<gath_blocks, 256, 0, stream>>>((const unsigned int*)hw, b,
                                                       row_ptr, csr_src, a_hi, a_lo);
        gru_fused_kernel<<<t32_blocks, 256, 0, stream>>>(a_hi, a_lo, h_hi, h_lo,
                                                         Wihb, Whhb, b_ih, b_hh,
                                                         Wb, hw, (s < 2) ? 1 : 0);
    }
    finalize_kernel<<<elem_blocks, 256, 0, stream>>>(h_hi, h_lo, (float*)d_out);
}

// Round 8
// 848.353 us; speedup vs baseline: 14.7155x; 1.1363x over previous
//
#include <hip/hip_runtime.h>
#include <math.h>

#define N_NODES 100000
#define N_EDGES 1600000

typedef __attribute__((ext_vector_type(8))) short short8;
typedef __attribute__((ext_vector_type(4))) float f32x4;

__device__ inline unsigned short f32_to_bf16(float x) {
    unsigned u = __float_as_uint(x);
    unsigned r = u + 0x7fff + ((u >> 16) & 1);   // RNE
    return (unsigned short)(r >> 16);
}
__device__ inline float bf16_to_f32(unsigned short u) {
    return __uint_as_float(((unsigned)u) << 16);
}
__device__ inline void split1(float x, unsigned short& hi, unsigned short& lo) {
    hi = f32_to_bf16(x);
    lo = f32_to_bf16(x - bf16_to_f32(hi));
}

// ---------------------------------------------------------------- cvt -------
__global__ __launch_bounds__(256) void cvt_bf16_kernel(const float* __restrict__ in,
                                                       unsigned short* __restrict__ out,
                                                       int n) {
    int i = blockIdx.x * 256 + threadIdx.x;
    if (i < n) out[i] = f32_to_bf16(in[i]);
}

// ---------------------------------------------------------------- init h ----
__global__ __launch_bounds__(256) void init_h_kernel(const float* __restrict__ f,
                                                     unsigned short* __restrict__ h_hi,
                                                     unsigned short* __restrict__ h_lo) {
    int idx = blockIdx.x * 256 + threadIdx.x;          // over N*32 float4
    if (idx >= N_NODES * 32) return;
    int r = idx >> 5, c4 = idx & 31;
    float4 v = make_float4(0.f, 0.f, 0.f, 0.f);
    if (c4 < 16) v = ((const float4*)f)[r * 16 + c4];
    ushort4 hv, lv;
    split1(v.x, hv.x, lv.x); split1(v.y, hv.y, lv.y);
    split1(v.z, hv.z, lv.z); split1(v.w, hv.w, lv.w);
    ((ushort4*)h_hi)[idx] = hv;
    ((ushort4*)h_lo)[idx] = lv;
}

// ---------------------------------------------------------------- finalize --
__global__ __launch_bounds__(256) void finalize_kernel(const unsigned short* __restrict__ h_hi,
                                                       const unsigned short* __restrict__ h_lo,
                                                       float* __restrict__ out) {
    int idx = blockIdx.x * 256 + threadIdx.x;          // over N*32 quads
    if (idx >= N_NODES * 32) return;
    ushort4 hv = ((const ushort4*)h_hi)[idx];
    ushort4 lv = ((const ushort4*)h_lo)[idx];
    float4 o;
    o.x = bf16_to_f32(hv.x) + bf16_to_f32(lv.x);
    o.y = bf16_to_f32(hv.y) + bf16_to_f32(lv.y);
    o.z = bf16_to_f32(hv.z) + bf16_to_f32(lv.z);
    o.w = bf16_to_f32(hv.w) + bf16_to_f32(lv.w);
    ((float4*)out)[idx] = o;
}

// ---------------------------------------------------------------- CSR build -
__global__ __launch_bounds__(256) void hist_kernel(const int* __restrict__ dst,
                                                   int* __restrict__ cnt) {
    int e = blockIdx.x * 256 + threadIdx.x;
    if (e < N_EDGES) atomicAdd(&cnt[dst[e]], 1);
}

__global__ __launch_bounds__(1024) void scanA_kernel(const int* __restrict__ cnt,
                                                     int* __restrict__ row_ptr,
                                                     int* __restrict__ blocksum) {
    __shared__ int sm[1024];
    int i = blockIdx.x * 1024 + threadIdx.x;
    int v = (i < N_NODES) ? cnt[i] : 0;
    sm[threadIdx.x] = v;
    __syncthreads();
    for (int off = 1; off < 1024; off <<= 1) {
        int t = (threadIdx.x >= off) ? sm[threadIdx.x - off] : 0;
        __syncthreads();
        sm[threadIdx.x] += t;
        __syncthreads();
    }
    if (i < N_NODES) row_ptr[i + 1] = sm[threadIdx.x];   // block-local inclusive
    if (threadIdx.x == 1023) blocksum[blockIdx.x] = sm[1023];
}

__global__ __launch_bounds__(128) void scanB_kernel(const int* __restrict__ blocksum,
                                                    int* __restrict__ blockoff, int nb) {
    __shared__ int sm[128];
    int v = (threadIdx.x < nb) ? blocksum[threadIdx.x] : 0;
    sm[threadIdx.x] = v;
    __syncthreads();
    for (int off = 1; off < 128; off <<= 1) {
        int t = (threadIdx.x >= off) ? sm[threadIdx.x - off] : 0;
        __syncthreads();
        sm[threadIdx.x] += t;
        __syncthreads();
    }
    if (threadIdx.x < nb) blockoff[threadIdx.x] = sm[threadIdx.x] - v;  // exclusive
}

__global__ __launch_bounds__(256) void scanC_kernel(const int* __restrict__ blockoff,
                                                    int* __restrict__ cnt_cursor,
                                                    int* __restrict__ row_ptr) {
    int i = blockIdx.x * 256 + threadIdx.x;
    if (i >= N_NODES) return;
    int incl = row_ptr[i + 1] + blockoff[i >> 10];
    row_ptr[i + 1] = incl;
    cnt_cursor[i] = incl - cnt_cursor[i];     // exclusive prefix -> fill cursor
    if (i == 0) row_ptr[0] = 0;
}

__global__ __launch_bounds__(256) void fill_kernel(const int* __restrict__ src,
                                                   const int* __restrict__ dst,
                                                   int* __restrict__ cursor,
                                                   int* __restrict__ csr_src) {
    int e = blockIdx.x * 256 + threadIdx.x;
    if (e >= N_EDGES) return;
    int pos = atomicAdd(&cursor[dst[e]], 1);
    csr_src[pos] = src[e];
}

// ---------------------------------------------------------------- hw GEMM ---
// hw(bf16) = (h_hi+h_lo) @ Wb.T   (initial step only). Block=16 nodes, no LDS.
__global__ __launch_bounds__(256) void gemm_hw_kernel(const unsigned short* __restrict__ h_hi,
                                                      const unsigned short* __restrict__ h_lo,
                                                      const unsigned short* __restrict__ Wb,
                                                      unsigned short* __restrict__ hw) {
    const int lane = threadIdx.x & 63;
    const int w    = threadIdx.x >> 6;
    const int l15  = lane & 15, hi8 = lane >> 4;
    const int n0   = blockIdx.x * 16;
    const int cw   = w * 32;

    f32x4 acc0 = {0.f, 0.f, 0.f, 0.f};
    f32x4 acc1 = {0.f, 0.f, 0.f, 0.f};
#pragma unroll
    for (int k0 = 0; k0 < 128; k0 += 32) {
        short8 ah = *(const short8*)&h_hi[(size_t)(n0 + l15) * 128 + k0 + hi8 * 8];
        short8 al = *(const short8*)&h_lo[(size_t)(n0 + l15) * 128 + k0 + hi8 * 8];
        short8 b0 = *(const short8*)&Wb[(size_t)(cw + l15) * 128 + k0 + hi8 * 8];
        short8 b1 = *(const short8*)&Wb[(size_t)(cw + 16 + l15) * 128 + k0 + hi8 * 8];
        acc0 = __builtin_amdgcn_mfma_f32_16x16x32_bf16(ah, b0, acc0, 0, 0, 0);
        acc0 = __builtin_amdgcn_mfma_f32_16x16x32_bf16(al, b0, acc0, 0, 0, 0);
        acc1 = __builtin_amdgcn_mfma_f32_16x16x32_bf16(ah, b1, acc1, 0, 0, 0);
        acc1 = __builtin_amdgcn_mfma_f32_16x16x32_bf16(al, b1, acc1, 0, 0, 0);
    }
#pragma unroll
    for (int r = 0; r < 4; ++r) {
        int row = n0 + hi8 * 4 + r;
        hw[(size_t)row * 128 + cw + l15]      = f32_to_bf16(acc0[r]);
        hw[(size_t)row * 128 + cw + 16 + l15] = f32_to_bf16(acc1[r]);
    }
}

// ---------------------------------------------------------------- gather ----
// a_pair[n] = split( sum_{in-edges} hw[src] + deg*b )   one wave per node.
__global__ __launch_bounds__(256) void gather_kernel(const unsigned int* __restrict__ hw,
                                                     const float* __restrict__ b,
                                                     const int* __restrict__ row_ptr,
                                                     const int* __restrict__ csr_src,
                                                     unsigned short* __restrict__ a_hi,
                                                     unsigned short* __restrict__ a_lo) {
    int node = blockIdx.x * 4 + (threadIdx.x >> 6);
    int lane = threadIdx.x & 63;
    int beg = row_ptr[node], end = row_ptr[node + 1];
    float a0 = 0.f, a1 = 0.f;
    int i = beg;
    for (; i + 3 < end; i += 4) {
        int e0 = csr_src[i], e1 = csr_src[i + 1];
        int e2 = csr_src[i + 2], e3 = csr_src[i + 3];
        unsigned u0 = hw[(size_t)e0 * 64 + lane];
        unsigned u1 = hw[(size_t)e1 * 64 + lane];
        unsigned u2 = hw[(size_t)e2 * 64 + lane];
        unsigned u3 = hw[(size_t)e3 * 64 + lane];
        a0 += __uint_as_float(u0 << 16) + __uint_as_float(u1 << 16)
            + __uint_as_float(u2 << 16) + __uint_as_float(u3 << 16);
        a1 += __uint_as_float(u0 & 0xffff0000u) + __uint_as_float(u1 & 0xffff0000u)
            + __uint_as_float(u2 & 0xffff0000u) + __uint_as_float(u3 & 0xffff0000u);
    }
    for (; i < end; ++i) {
        unsigned u0 = hw[(size_t)csr_src[i] * 64 + lane];
        a0 += __uint_as_float(u0 << 16);
        a1 += __uint_as_float(u0 & 0xffff0000u);
    }
    float deg = (float)(end - beg);
    float2 bb = ((const float2*)b)[lane];
    unsigned short h0, l0, h1, l1;
    split1(a0 + deg * bb.x, h0, l0);
    split1(a1 + deg * bb.y, h1, l1);
    ((ushort2*)a_hi)[(size_t)node * 64 + lane] = (ushort2){h0, h1};
    ((ushort2*)a_lo)[(size_t)node * 64 + lane] = (ushort2){l0, l1};
}

// ---------------------------------------------------------------- GRU -------
// Weight-stationary persistent GRU. Grid=256 blocks (1/CU), 1 wave/SIMD.
// Each wave holds its 32-col slice of Wih/Whh/Wb in registers, then
// grid-strides over 6250 16-node tiles.
// RACE NOTE: the MFMA phase reads h rows across ALL columns; the gates phase
// writes h. A __syncthreads() between them is REQUIRED (round-7 failure:
// dropping it let drifted waves mix old/new h).
#define SLDS 136   // padded LDS row stride (shorts)
__global__ __launch_bounds__(256, 1) void gru_ws_kernel(
        const unsigned short* __restrict__ a_hi,
        const unsigned short* __restrict__ a_lo,
        unsigned short* __restrict__ h_hi,
        unsigned short* __restrict__ h_lo,
        const unsigned short* __restrict__ Wihb,
        const unsigned short* __restrict__ Whhb,
        const float* __restrict__ b_ih,
        const float* __restrict__ b_hh,
        const unsigned short* __restrict__ Wb,
        unsigned short* __restrict__ hw_out,
        int make_hw) {
    __shared__ unsigned short s_hi[16 * SLDS];
    __shared__ unsigned short s_lo[16 * SLDS];

    const int lane = threadIdx.x & 63;
    const int w    = threadIdx.x >> 6;
    const int l15  = lane & 15, hi8 = lane >> 4;
    const int cw   = w * 32;

    // ---- stationary weights: per-wave 32-col slice, in registers
    short8 wi[3][2][4], wh[3][2][4];
#pragma unroll
    for (int g = 0; g < 3; ++g)
#pragma unroll
        for (int t = 0; t < 2; ++t)
#pragma unroll
            for (int k0 = 0; k0 < 4; ++k0) {
                size_t wro = (size_t)(g * 128 + cw + t * 16 + l15) * 128 + k0 * 32 + hi8 * 8;
                wi[g][t][k0] = *(const short8*)&Wihb[wro];
                wh[g][t][k0] = *(const short8*)&Whhb[wro];
            }
    short8 wb0[4], wb1[4];
#pragma unroll
    for (int k0 = 0; k0 < 4; ++k0) {
        wb0[k0] = *(const short8*)&Wb[(size_t)(cw + l15) * 128 + k0 * 32 + hi8 * 8];
        wb1[k0] = *(const short8*)&Wb[(size_t)(cw + 16 + l15) * 128 + k0 * 32 + hi8 * 8];
    }
    // ---- stationary biases
    float bir[2], biz[2], bin[2], bhr[2], bhz[2], bhn[2];
#pragma unroll
    for (int t = 0; t < 2; ++t) {
        int c = cw + t * 16 + l15;
        bir[t] = b_ih[c]; biz[t] = b_ih[128 + c]; bin[t] = b_ih[256 + c];
        bhr[t] = b_hh[c]; bhz[t] = b_hh[128 + c]; bhn[t] = b_hh[256 + c];
    }

    for (int tile = blockIdx.x; tile < N_NODES / 16; tile += gridDim.x) {
        const int n0 = tile * 16;

        // ---- load a/h split fragments for this tile
        short8 ah[4], al[4], hh8[4], hl8[4];
#pragma unroll
        for (int k0 = 0; k0 < 4; ++k0) {
            size_t ro = (size_t)(n0 + l15) * 128 + k0 * 32 + hi8 * 8;
            ah[k0]  = *(const short8*)&a_hi[ro];
            al[k0]  = *(const short8*)&a_lo[ro];
            hh8[k0] = *(const short8*)&h_hi[ro];
            hl8[k0] = *(const short8*)&h_lo[ro];
        }

        // ---- GRU GEMMs (weights in registers)
        f32x4 z1[3][2], z2[3][2];
#pragma unroll
        for (int g = 0; g < 3; ++g)
#pragma unroll
            for (int t = 0; t < 2; ++t) {
                z1[g][t] = (f32x4){0.f, 0.f, 0.f, 0.f};
                z2[g][t] = (f32x4){0.f, 0.f, 0.f, 0.f};
            }
#pragma unroll
        for (int k0 = 0; k0 < 4; ++k0)
#pragma unroll
            for (int g = 0; g < 3; ++g)
#pragma unroll
                for (int t = 0; t < 2; ++t) {
                    z1[g][t] = __builtin_amdgcn_mfma_f32_16x16x32_bf16(ah[k0],  wi[g][t][k0], z1[g][t], 0, 0, 0);
                    z1[g][t] = __builtin_amdgcn_mfma_f32_16x16x32_bf16(al[k0],  wi[g][t][k0], z1[g][t], 0, 0, 0);
                    z2[g][t] = __builtin_amdgcn_mfma_f32_16x16x32_bf16(hh8[k0], wh[g][t][k0], z2[g][t], 0, 0, 0);
                    z2[g][t] = __builtin_amdgcn_mfma_f32_16x16x32_bf16(hl8[k0], wh[g][t][k0], z2[g][t], 0, 0, 0);
                }

        // ---- BARRIER: all waves' h/a reads complete before any h write
        __syncthreads();

        // ---- gates + h pair update (+ LDS copy for the epilogue GEMM)
#pragma unroll
        for (int t = 0; t < 2; ++t) {
            int c = cw + t * 16 + l15;
#pragma unroll
            for (int r = 0; r < 4; ++r) {
                int lrow = hi8 * 4 + r;
                size_t gidx = (size_t)(n0 + lrow) * 128 + c;
                float hold = bf16_to_f32(h_hi[gidx]) + bf16_to_f32(h_lo[gidx]);
                float rr = 1.f / (1.f + __expf(-(z1[0][t][r] + bir[t] + z2[0][t][r] + bhr[t])));
                float zz = 1.f / (1.f + __expf(-(z1[1][t][r] + biz[t] + z2[1][t][r] + bhz[t])));
                float nn_ = tanhf(z1[2][t][r] + bin[t] + rr * (z2[2][t][r] + bhn[t]));
                float hn = (1.f - zz) * nn_ + zz * hold;
                unsigned short sh, sl;
                split1(hn, sh, sl);
                h_hi[gidx] = sh;
                h_lo[gidx] = sl;
                if (make_hw) {
                    s_hi[lrow * SLDS + c] = sh;
                    s_lo[lrow * SLDS + c] = sl;
                }
            }
        }

        // ---- hw for next step (LDS transpose -> MFMA with register Wb)
        if (make_hw) {
            __syncthreads();
            f32x4 c0 = {0.f, 0.f, 0.f, 0.f};
            f32x4 c1 = {0.f, 0.f, 0.f, 0.f};
#pragma unroll
            for (int k0 = 0; k0 < 4; ++k0) {
                short8 xh = *(const short8*)&s_hi[l15 * SLDS + k0 * 32 + hi8 * 8];
                short8 xl = *(const short8*)&s_lo[l15 * SLDS + k0 * 32 + hi8 * 8];
                c0 = __builtin_amdgcn_mfma_f32_16x16x32_bf16(xh, wb0[k0], c0, 0, 0, 0);
                c0 = __builtin_amdgcn_mfma_f32_16x16x32_bf16(xl, wb0[k0], c0, 0, 0, 0);
                c1 = __builtin_amdgcn_mfma_f32_16x16x32_bf16(xh, wb1[k0], c1, 0, 0, 0);
                c1 = __builtin_amdgcn_mfma_f32_16x16x32_bf16(xl, wb1[k0], c1, 0, 0, 0);
            }
#pragma unroll
            for (int r = 0; r < 4; ++r) {
                int row = n0 + hi8 * 4 + r;
                hw_out[(size_t)row * 128 + cw + l15]      = f32_to_bf16(c0[r]);
                hw_out[(size_t)row * 128 + cw + 16 + l15] = f32_to_bf16(c1[r]);
            }
            __syncthreads();   // LDS reused by next tile
        }
    }
}

// ---------------------------------------------------------------- launch ----
extern "C" void kernel_launch(void* const* d_in, const int* in_sizes, int n_in,
                              void* d_out, int out_size, void* d_ws, size_t ws_size,
                              hipStream_t stream) {
    const float* feat = (const float*)d_in[0];
    const float* W    = (const float*)d_in[1];
    const float* b    = (const float*)d_in[2];
    const float* W_ih = (const float*)d_in[3];
    const float* W_hh = (const float*)d_in[4];
    const float* b_ih = (const float*)d_in[5];
    const float* b_hh = (const float*)d_in[6];
    const int*   src  = (const int*)d_in[7];
    const int*   dst  = (const int*)d_in[8];

    // a-pair parks in d_out during the steps (exact fit: N*128*4 bytes);
    // finalize_kernel rewrites d_out with f32 h at the end.
    unsigned short* a_hi = (unsigned short*)d_out;
    unsigned short* a_lo = a_hi + (size_t)N_NODES * 128;

    char* w = (char*)d_ws;
    unsigned short* h_hi  = (unsigned short*)w; w += (size_t)N_NODES * 128 * 2;
    unsigned short* h_lo  = (unsigned short*)w; w += (size_t)N_NODES * 128 * 2;
    unsigned short* hw    = (unsigned short*)w; w += (size_t)N_NODES * 128 * 2;
    unsigned short* Wb    = (unsigned short*)w; w += (size_t)128 * 128 * 2;
    unsigned short* Wihb  = (unsigned short*)w; w += (size_t)384 * 128 * 2;
    unsigned short* Whhb  = (unsigned short*)w; w += (size_t)384 * 128 * 2;
    int*            csr_src  = (int*)w;         w += (size_t)N_EDGES * 4;
    int*            row_ptr  = (int*)w;         w += ((size_t)N_NODES + 4) * 4;
    int*            cnt      = (int*)w;         w += (size_t)N_NODES * 4;
    int*            blocksum = (int*)w;         w += 128 * 4;
    int*            blockoff = (int*)w;

    const int elem_blocks  = (N_NODES * 32 + 255) / 256;
    const int t16_blocks   = N_NODES / 16;                 // 6250 (exact)
    const int edge_blocks  = (N_EDGES + 255) / 256;
    const int node_blocks  = (N_NODES + 255) / 256;
    const int scanA_blocks = (N_NODES + 1023) / 1024;      // 98
    const int gath_blocks  = N_NODES / 4;                  // 25000 (exact)

    init_h_kernel<<<elem_blocks, 256, 0, stream>>>(feat, h_hi, h_lo);
    cvt_bf16_kernel<<<(128 * 128 + 255) / 256, 256, 0, stream>>>(W, Wb, 128 * 128);
    cvt_bf16_kernel<<<(384 * 128 + 255) / 256, 256, 0, stream>>>(W_ih, Wihb, 384 * 128);
    cvt_bf16_kernel<<<(384 * 128 + 255) / 256, 256, 0, stream>>>(W_hh, Whhb, 384 * 128);

    // ---- CSR by dst (graph static across the 3 steps)
    hipMemsetAsync(cnt, 0, (size_t)N_NODES * 4, stream);
    hist_kernel<<<edge_blocks, 256, 0, stream>>>(dst, cnt);
    scanA_kernel<<<scanA_blocks, 1024, 0, stream>>>(cnt, row_ptr, blocksum);
    scanB_kernel<<<1, 128, 0, stream>>>(blocksum, blockoff, scanA_blocks);
    scanC_kernel<<<node_blocks, 256, 0, stream>>>(blockoff, cnt, row_ptr);
    fill_kernel<<<edge_blocks, 256, 0, stream>>>(src, dst, cnt, csr_src);

    // ---- initial hw, then 3 steps
    gemm_hw_kernel<<<t16_blocks, 256, 0, stream>>>(h_hi, h_lo, Wb, hw);
    for (int s = 0; s < 3; ++s) {
        gather_kernel<<<gath_blocks, 256, 0, stream>>>((const unsigned int*)hw, b,
                                                       row_ptr, csr_src, a_hi, a_lo);
        gru_ws_kernel<<<256, 256, 0, stream>>>(a_hi, a_lo, h_hi, h_lo,
                                               Wihb, Whhb, b_ih, b_hh,
                                               Wb, hw, (s < 2) ? 1 : 0);
    }
    finalize_kernel<<<elem_blocks, 256, 0, stream>>>(h_hi, h_lo, (float*)d_out);
}